// Round 8
// baseline (552.053 us; speedup 1.0000x reference)
//
#include <hip/hip_runtime.h>
#include <math.h>

#define NND 50000
#define NE  1200000
#define NG  256
#define H   64
#define H2  128
#define H4  256
#define H8  512
#define FIN 5
#define EPS_BN 1e-5f
#define EPS_MSG 1e-7f
#define NB 196          // ceil(NND/256)
#define NXP 8           // buckets / XCD partitions
#define DPART 6250      // NND / NXP
#define PC 8            // pool chunks per graph
#define MT 64           // nodes per mlp block
#define BCAP 160000     // bucket capacity (E/8 = 150000 expected, 27 sigma margin)
#define NBK 625         // BCAP / 256

typedef _Float16 half8 __attribute__((ext_vector_type(8)));
typedef float floatx4 __attribute__((ext_vector_type(4)));

// ---------------- CSR build: bucket -> count -> scan -> scatter ----------------

__global__ void k_zero(int* counts, int* bcur) {
    int n = blockIdx.x * blockDim.x + threadIdx.x;
    if (n < NND) counts[n] = 0;
    if (n < NXP) bcur[n] = 0;
}

// one pass: partition edges into 8 dst-range buckets, coalesced appends
__global__ void k_bucket(const int* __restrict__ ei, int* bcur, uint2* __restrict__ ebuf) {
    __shared__ int lcnt[NXP];
    __shared__ int lbase[NXP];
    int t = threadIdx.x;
    int e = blockIdx.x * 256 + t;
    if (t < NXP) lcnt[t] = 0;
    __syncthreads();
    int s = 0, d = 0, bkt = 0, my = 0;
    bool v = e < NE;
    if (v) {
        s = ei[e]; d = ei[NE + e];
        bkt = d / DPART;
        my = atomicAdd(&lcnt[bkt], 1);
    }
    __syncthreads();
    if (t < NXP) lbase[t] = atomicAdd(&bcur[t], lcnt[t]);
    __syncthreads();
    if (v) {
        int pos = lbase[bkt] + my;
        if (pos < BCAP) ebuf[(size_t)bkt * BCAP + pos] = make_uint2((unsigned)s, (unsigned)d);
    }
}

// grid 8*NBK; block b handles bucket b&7 -> atomics confined to 25KB slice (one XCD L2)
__global__ void k_count_b(const int* __restrict__ bcur, const uint2* __restrict__ ebuf,
                          int* counts) {
    int b = blockIdx.x;
    int bkt = b & (NXP - 1);
    int i = (b >> 3) * 256 + threadIdx.x;
    if (i >= bcur[bkt]) return;
    uint2 ed = ebuf[(size_t)bkt * BCAP + i];
    atomicAdd(&counts[ed.y], 1);
}

__global__ void k_scan1(const int* __restrict__ counts, int* __restrict__ rowptr,
                        int* __restrict__ bsum) {
    __shared__ int wsum[4];
    int b = blockIdx.x, t = threadIdx.x;
    int i = b * 256 + t;
    int v = (i < NND) ? counts[i] : 0;
    int lane = t & 63, wid = t >> 6;
    int sv = v;
#pragma unroll
    for (int off = 1; off < 64; off <<= 1) {
        int x = __shfl_up(sv, off, 64);
        if (lane >= off) sv += x;
    }
    if (lane == 63) wsum[wid] = sv;
    __syncthreads();
    int woff = 0;
    for (int w = 0; w < wid; w++) woff += wsum[w];
    int inc = woff + sv;
    if (i < NND) rowptr[i + 1] = inc;
    if (t == 255) bsum[b] = inc;
}

__global__ void k_scan2(const int* __restrict__ bsum, int* __restrict__ boff,
                        int* __restrict__ rowptr) {
    __shared__ int wsum[4];
    int t = threadIdx.x;
    int v = (t < NB) ? bsum[t] : 0;
    int lane = t & 63, wid = t >> 6;
    int sv = v;
#pragma unroll
    for (int off = 1; off < 64; off <<= 1) {
        int x = __shfl_up(sv, off, 64);
        if (lane >= off) sv += x;
    }
    if (lane == 63) wsum[wid] = sv;
    __syncthreads();
    int woff = 0;
    for (int w = 0; w < wid; w++) woff += wsum[w];
    if (t < NB) boff[t] = woff + sv - v;
    if (t == 0) rowptr[0] = 0;
}

__global__ void k_scan3(const int* __restrict__ boff, const int* __restrict__ counts,
                        int* __restrict__ rowptr, int* __restrict__ next,
                        float* __restrict__ dinv) {
    int i = blockIdx.x * 256 + threadIdx.x;
    if (i >= NND) return;
    int r = rowptr[i + 1] + boff[i >> 8];
    rowptr[i + 1] = r;
    next[i] = r - counts[i];
    dinv[i] = rsqrtf((float)counts[i] + 1.0f);
}

__global__ void k_scatter_b(const int* __restrict__ bcur, const uint2* __restrict__ ebuf,
                            int* next, int* __restrict__ csr) {
    int b = blockIdx.x;
    int bkt = b & (NXP - 1);
    int i = (b >> 3) * 256 + threadIdx.x;
    if (i >= bcur[bkt]) return;
    uint2 ed = ebuf[(size_t)bkt * BCAP + i];
    int pos = atomicAdd(&next[ed.y], 1);
    csr[pos] = (int)ed.x;
}

// ---------------- weight pre-swizzle into MFMA B-frag layout ----------------

__global__ void k_wswz(const float* __restrict__ W1, const float* __restrict__ W2,
                       _Float16* __restrict__ w1f, _Float16* __restrict__ w2f) {
    int t = blockIdx.x * blockDim.x + threadIdx.x;   // 3*16*64 = 3072
    if (t >= 3 * 16 * 64) return;
    int lane = t & 63, fr = (t >> 6) & 15, l = t >> 10;
    {
        int jt = fr >> 1, kf = fr & 1;
        int j = jt * 16 + (lane & 15);
        int k0 = kf * 32 + (lane >> 4) * 8;
#pragma unroll
        for (int i = 0; i < 8; i++)
            w1f[(((size_t)l * 16 + jt * 2 + kf) * 64 + lane) * 8 + i] =
                (_Float16)W1[(size_t)l * H * H2 + (k0 + i) * H2 + j];
    }
    {
        int ct = fr >> 2, k2f = fr & 3;
        int c = ct * 16 + (lane & 15);
        int k0 = k2f * 32 + (lane >> 4) * 8;
#pragma unroll
        for (int i = 0; i < 8; i++)
            w2f[(((size_t)l * 16 + ct * 4 + k2f) * 64 + lane) * 8 + i] =
                (_Float16)W2[(size_t)l * H2 * H + (k0 + i) * H + c];
    }
}

// ---------------- GCNConv ----------------

__global__ void k_conv1(const float* __restrict__ x, const float* __restrict__ W,
                        float* __restrict__ t0, _Float16* __restrict__ t0h) {
    int tid = blockIdx.x * blockDim.x + threadIdx.x;
    if (tid >= NND * H) return;
    int n = tid >> 6, c = tid & 63;
    float acc = 0.f;
#pragma unroll
    for (int k = 0; k < FIN; k++) acc += x[n * FIN + k] * W[k * H + c];
    t0[n * H + c] = acc;
    t0h[n * H + c] = (_Float16)acc;
}

// wave per node; lane = 8*eg + q8: eg = edge subgroup (0..7), q8 = channel octet
__global__ void k_gcn(const int* __restrict__ rowptr, const int* __restrict__ csr,
                      const float* __restrict__ t0, const _Float16* __restrict__ t0h,
                      const float* __restrict__ dinv,
                      const float* __restrict__ cb, const float* __restrict__ bg,
                      const float* __restrict__ bb,
                      const float* __restrict__ lg, const float* __restrict__ lb,
                      const float* __restrict__ pa,
                      float* __restrict__ xc, float* __restrict__ u,
                      _Float16* __restrict__ u_h) {
    int d = (blockIdx.x * blockDim.x + threadIdx.x) >> 6;
    int lane = threadIdx.x & 63;
    if (d >= NND) return;
    int q8 = lane & 7, eg = lane >> 3;
    int beg = rowptr[d], end = rowptr[d + 1];
    float acc[8];
#pragma unroll
    for (int k = 0; k < 8; k++) acc[k] = 0.f;
    for (int i0 = beg; i0 < end; i0 += 64) {
        int idx = i0 + lane;
        int csrv = 0; float dvv = 0.f;
        if (idx < end) { csrv = csr[idx]; dvv = dinv[csrv]; }
        int chunk = min(64, end - i0);
        for (int j = 0; j < chunk; j += 8) {
            int e_rel = j + eg;
            int s  = __shfl(csrv, e_rel, 64);
            float dv = __shfl(dvv, e_rel, 64);
            if (i0 + e_rel < end) {
                half8 hv = *(const half8*)&t0h[(size_t)s * H + 8 * q8];
#pragma unroll
                for (int k = 0; k < 8; k++) acc[k] += (float)hv[k] * dv;
            }
        }
    }
#pragma unroll
    for (int off = 8; off <= 32; off <<= 1)
#pragma unroll
        for (int k = 0; k < 8; k++) acc[k] += __shfl_xor(acc[k], off, 64);
    if (eg == 0) {
        int c0 = 8 * q8;
        float dd = dinv[d];
        float bns = rsqrtf(1.f + EPS_BN);
        float4 ts0 = *(const float4*)&t0[d * H + c0];
        float4 ts1 = *(const float4*)&t0[d * H + c0 + 4];
        float self[8] = {ts0.x, ts0.y, ts0.z, ts0.w, ts1.x, ts1.y, ts1.z, ts1.w};
        float x0[8];
        float sum = 0.f, sq = 0.f;
#pragma unroll
        for (int k = 0; k < 8; k++) {
            int c = c0 + k;
            float v = acc[k] * dd + self[k] * dd * dd + cb[c];
            v = v * (bg[c] * bns) + bb[c];
            v = fmaxf(v, 0.f);
            x0[k] = v;
            sum += v; sq += v * v;
        }
        *(float4*)&xc[(size_t)d * H4 + c0] = make_float4(x0[0], x0[1], x0[2], x0[3]);
        *(float4*)&xc[(size_t)d * H4 + c0 + 4] = make_float4(x0[4], x0[5], x0[6], x0[7]);
#pragma unroll
        for (int off = 1; off <= 4; off <<= 1) {
            sum += __shfl_xor(sum, off, 64);
            sq  += __shfl_xor(sq,  off, 64);
        }
        float mu  = sum * (1.f / H);
        float var = sq * (1.f / H) - mu * mu;
        float rs = rsqrtf(var + EPS_BN);
        float y[8];
        half8 yh;
#pragma unroll
        for (int k = 0; k < 8; k++) {
            int c = c0 + k;
            float yy = (x0[k] - mu) * rs * lg[c] + lb[c];
            yy = (yy >= 0.f) ? yy : pa[c] * yy;
            y[k] = yy;
            yh[k] = (_Float16)yy;
        }
        *(float4*)&u[d * H + c0] = make_float4(y[0], y[1], y[2], y[3]);
        *(float4*)&u[d * H + c0 + 4] = make_float4(y[4], y[5], y[6], y[7]);
        *(half8*)&u_h[(size_t)d * H + c0] = yh;
    }
}

// ---------------- GENConv softmax aggregation (f16 gather, 8 edges/instr) ----------------

__global__ void k_gen(const int* __restrict__ rowptr, const int* __restrict__ csr,
                      const float* __restrict__ u, const _Float16* __restrict__ u_h,
                      const float* __restrict__ tptr, int li, float* __restrict__ ua) {
    int d = (blockIdx.x * blockDim.x + threadIdx.x) >> 6;
    int lane = threadIdx.x & 63;
    if (d >= NND) return;
    int q8 = lane & 7, eg = lane >> 3;
    float t = tptr[li];
    int beg = rowptr[d], end = rowptr[d + 1];
    float s8[8], n8[8];
#pragma unroll
    for (int k = 0; k < 8; k++) { s8[k] = 0.f; n8[k] = 0.f; }
    for (int i0 = beg; i0 < end; i0 += 64) {
        int idx = i0 + lane;
        int csrv = (idx < end) ? csr[idx] : 0;
        int chunk = min(64, end - i0);
        for (int j = 0; j < chunk; j += 8) {
            int e_rel = j + eg;
            int s = __shfl(csrv, e_rel, 64);
            if (i0 + e_rel < end) {
                half8 hv = *(const half8*)&u_h[(size_t)s * H + 8 * q8];
#pragma unroll
                for (int k = 0; k < 8; k++) {
                    float m = fmaxf((float)hv[k], 0.f) + EPS_MSG;
                    float e = __expf(m * t - 8.f);
                    s8[k] += e;
                    n8[k] += m * e;
                }
            }
        }
    }
#pragma unroll
    for (int off = 8; off <= 32; off <<= 1)
#pragma unroll
        for (int k = 0; k < 8; k++) {
            s8[k] += __shfl_xor(s8[k], off, 64);
            n8[k] += __shfl_xor(n8[k], off, 64);
        }
    if (eg == 0) {
        int c0 = 8 * q8;
        float4 us0 = *(const float4*)&u[d * H + c0];
        float4 us1 = *(const float4*)&u[d * H + c0 + 4];
        float us[8] = {us0.x, us0.y, us0.z, us0.w, us1.x, us1.y, us1.z, us1.w};
        float o[8];
#pragma unroll
        for (int k = 0; k < 8; k++)
            o[k] = us[k] + ((s8[k] > 0.f) ? n8[k] / s8[k] : 0.f);
        *(float4*)&ua[d * H + c0] = make_float4(o[0], o[1], o[2], o[3]);
        *(float4*)&ua[d * H + c0 + 4] = make_float4(o[4], o[5], o[6], o[7]);
    }
}

// ---------------- fused MLP via MFMA (f16 inputs, f32 accumulate) ----------------

__global__ void __launch_bounds__(256)
k_mlp(const float* __restrict__ ua,
      const _Float16* __restrict__ w1f, const _Float16* __restrict__ w2f,
      const float* __restrict__ b1,
      const float* __restrict__ bng, const float* __restrict__ bnb,
      const float* __restrict__ b2,
      float* __restrict__ xc, int slice,
      const float* __restrict__ lg, const float* __restrict__ lb,
      const float* __restrict__ pa, float* __restrict__ u_next,
      _Float16* __restrict__ u_h, int do_ln) {
    __shared__ _Float16 a1[4][2][64][8];   // 8 KB  [mtile][kf][lane][i]
    __shared__ _Float16 a2[4][4][64][8];   // 16 KB [mtile][k2f][lane][i]
    int t = threadIdx.x;
    int w = t >> 6, l = t & 63;
    int nb = blockIdx.x * MT;
    int c_in = l & 15, quad = l >> 4;
    bool wvalid = (nb + 16 * w) < NND;

    {
        int n = t >> 2;
        int k0 = (t & 3) * 16;
        int gn = nb + n;
        float4 v0 = {0,0,0,0}, v1 = v0, v2 = v0, v3 = v0;
        if (gn < NND) {
            v0 = *(const float4*)&ua[gn * H + k0];
            v1 = *(const float4*)&ua[gn * H + k0 + 4];
            v2 = *(const float4*)&ua[gn * H + k0 + 8];
            v3 = *(const float4*)&ua[gn * H + k0 + 12];
        }
        int mt = n >> 4, kf = k0 >> 5, g0 = (k0 >> 3) & 3;
        half8 h0 = {(_Float16)v0.x, (_Float16)v0.y, (_Float16)v0.z, (_Float16)v0.w,
                    (_Float16)v1.x, (_Float16)v1.y, (_Float16)v1.z, (_Float16)v1.w};
        half8 h1 = {(_Float16)v2.x, (_Float16)v2.y, (_Float16)v2.z, (_Float16)v2.w,
                    (_Float16)v3.x, (_Float16)v3.y, (_Float16)v3.z, (_Float16)v3.w};
        *(half8*)&a1[mt][kf][(n & 15) + 16 * g0][0] = h0;
        *(half8*)&a1[mt][kf][(n & 15) + 16 * (g0 + 1)][0] = h1;
    }

    floatx4 acc[8];
#pragma unroll
    for (int jt = 0; jt < 8; jt++) acc[jt] = (floatx4){0.f, 0.f, 0.f, 0.f};
    half8 af0 = *(half8*)&a1[w][0][l][0];
    half8 af1 = *(half8*)&a1[w][1][l][0];
#pragma unroll
    for (int jt = 0; jt < 8; jt++) {
        half8 bf0 = *(const half8*)&w1f[((size_t)(jt * 2 + 0) * 64 + l) * 8];
        half8 bf1 = *(const half8*)&w1f[((size_t)(jt * 2 + 1) * 64 + l) * 8];
        acc[jt] = __builtin_amdgcn_mfma_f32_16x16x32_f16(af0, bf0, acc[jt], 0, 0, 0);
        acc[jt] = __builtin_amdgcn_mfma_f32_16x16x32_f16(af1, bf1, acc[jt], 0, 0, 0);
    }

    {
        float bns = rsqrtf(1.f + EPS_BN);
#pragma unroll
        for (int jt = 0; jt < 8; jt++) {
            int j = jt * 16 + c_in;
            float b1v = b1[j], bsv = bng[j] * bns, bbv = bnb[j];
            int kf2 = jt >> 1;
            int lp = 16 * ((2 * jt + (c_in >> 3)) & 3);
            int ii = c_in & 7;
#pragma unroll
            for (int reg = 0; reg < 4; reg++) {
                float z = fmaxf((acc[jt][reg] + b1v) * bsv + bbv, 0.f);
                a2[w][kf2][quad * 4 + reg + lp][ii] = (_Float16)z;
            }
        }
    }

    floatx4 acc2[4];
#pragma unroll
    for (int ct = 0; ct < 4; ct++) acc2[ct] = (floatx4){0.f, 0.f, 0.f, 0.f};
    half8 a2f[4];
#pragma unroll
    for (int k2f = 0; k2f < 4; k2f++) a2f[k2f] = *(half8*)&a2[w][k2f][l][0];
#pragma unroll
    for (int ct = 0; ct < 4; ct++) {
#pragma unroll
        for (int k2f = 0; k2f < 4; k2f++) {
            half8 bfr = *(const half8*)&w2f[((size_t)(ct * 4 + k2f) * 64 + l) * 8];
            acc2[ct] = __builtin_amdgcn_mfma_f32_16x16x32_f16(a2f[k2f], bfr, acc2[ct], 0, 0, 0);
        }
    }

    float vv[4][4];
#pragma unroll
    for (int ct = 0; ct < 4; ct++) {
        int c = ct * 16 + c_in;
        float b2v = b2[c];
#pragma unroll
        for (int reg = 0; reg < 4; reg++) {
            int node = nb + 16 * w + quad * 4 + reg;
            float v = 0.f;
            if (wvalid) {
                v = xc[(size_t)node * H4 + slice * H + c] + acc2[ct][reg] + b2v;
                xc[(size_t)node * H4 + (slice + 1) * H + c] = v;
            }
            vv[ct][reg] = v;
        }
    }
    if (do_ln) {
#pragma unroll
        for (int reg = 0; reg < 4; reg++) {
            float s = (vv[0][reg] + vv[1][reg]) + (vv[2][reg] + vv[3][reg]);
            float q = (vv[0][reg] * vv[0][reg] + vv[1][reg] * vv[1][reg]) +
                      (vv[2][reg] * vv[2][reg] + vv[3][reg] * vv[3][reg]);
#pragma unroll
            for (int off = 1; off <= 8; off <<= 1) {
                s += __shfl_xor(s, off, 64);
                q += __shfl_xor(q, off, 64);
            }
            float mu = s * (1.f / H);
            float var = q * (1.f / H) - mu * mu;
            float rs = rsqrtf(var + EPS_BN);
            int node = nb + 16 * w + quad * 4 + reg;
#pragma unroll
            for (int ct = 0; ct < 4; ct++) {
                int c = ct * 16 + c_in;
                float y = (vv[ct][reg] - mu) * rs * lg[c] + lb[c];
                y = (y >= 0.f) ? y : pa[c] * y;
                if (wvalid) {
                    u_next[node * H + c] = y;
                    u_h[(size_t)node * H + c] = (_Float16)y;
                }
            }
        }
    }
}

// ---------------- pooling + readout ----------------

__global__ void k_gbounds(const int* __restrict__ batch, int* __restrict__ gstart) {
    int g = threadIdx.x + blockIdx.x * blockDim.x;
    if (g > NG) return;
    int lo = 0, hi = NND;
    while (lo < hi) { int mid = (lo + hi) >> 1; if (batch[mid] < g) lo = mid + 1; else hi = mid; }
    gstart[g] = lo;
}

__global__ void __launch_bounds__(256)
k_pool1(const float* __restrict__ xc, const int* __restrict__ gstart,
        float* __restrict__ psum_p, float* __restrict__ pmax_p) {
    __shared__ float4 ssum[256];
    __shared__ float4 smax[256];
    int b = blockIdx.x;
    int g = b >> 3, k = b & (PC - 1);
    int t = threadIdx.x;
    int start = gstart[g], end = gstart[g + 1];
    int len = end - start;
    int c0 = start + (len * k) / PC;
    int c1 = start + (len * (k + 1)) / PC;
    int q = t & 63, sub = t >> 6;
    float4 sum = {0.f, 0.f, 0.f, 0.f};
    float4 mx = {-INFINITY, -INFINITY, -INFINITY, -INFINITY};
    for (int n = c0 + sub; n < c1; n += 4) {
        float4 v = *(const float4*)&xc[(size_t)n * H4 + 4 * q];
        sum.x += v.x; sum.y += v.y; sum.z += v.z; sum.w += v.w;
        mx.x = fmaxf(mx.x, v.x); mx.y = fmaxf(mx.y, v.y);
        mx.z = fmaxf(mx.z, v.z); mx.w = fmaxf(mx.w, v.w);
    }
    ssum[t] = sum; smax[t] = mx;
    __syncthreads();
    if (t < 64) {
        float4 s0 = ssum[t], s1 = ssum[t + 64], s2 = ssum[t + 128], s3 = ssum[t + 192];
        float4 m0 = smax[t], m1 = smax[t + 64], m2 = smax[t + 128], m3 = smax[t + 192];
        float4 S, M;
        S.x = (s0.x + s1.x) + (s2.x + s3.x);
        S.y = (s0.y + s1.y) + (s2.y + s3.y);
        S.z = (s0.z + s1.z) + (s2.z + s3.z);
        S.w = (s0.w + s1.w) + (s2.w + s3.w);
        M.x = fmaxf(fmaxf(m0.x, m1.x), fmaxf(m2.x, m3.x));
        M.y = fmaxf(fmaxf(m0.y, m1.y), fmaxf(m2.y, m3.y));
        M.z = fmaxf(fmaxf(m0.z, m1.z), fmaxf(m2.z, m3.z));
        M.w = fmaxf(fmaxf(m0.w, m1.w), fmaxf(m2.w, m3.w));
        *(float4*)&psum_p[(size_t)b * H4 + 4 * q] = S;
        *(float4*)&pmax_p[(size_t)b * H4 + 4 * q] = M;
    }
}

__global__ void __launch_bounds__(256)
k_readout(const float* __restrict__ psum_p, const float* __restrict__ pmax_p,
          const int* __restrict__ gstart,
          const float* __restrict__ W1, const float* __restrict__ b1,
          const float* __restrict__ W2, const float* __restrict__ b2,
          const float* __restrict__ Wo, const float* __restrict__ bo,
          float* __restrict__ out) {
    __shared__ float p0_l[H8];
    __shared__ float p1part[2][H2];
    __shared__ float p1_l[H2];
    __shared__ float p2part[4][H];
    __shared__ float p2_l[H];
    int g = blockIdx.x;
    int t = threadIdx.x;

    {
        float s = 0.f, m = -INFINITY;
#pragma unroll
        for (int k = 0; k < PC; k++) {
            s += psum_p[(size_t)(g * PC + k) * H4 + t];
            m = fmaxf(m, pmax_p[(size_t)(g * PC + k) * H4 + t]);
        }
        int cnt = gstart[g + 1] - gstart[g];
        p0_l[t] = s / fmaxf((float)cnt, 1.f);
        p0_l[H4 + t] = (cnt > 0) ? m : 0.f;
    }
    __syncthreads();

    {
        int j = t & 127, h = t >> 7;
        float acc = 0.f;
        int k0 = h * 256;
        for (int k = 0; k < 256; k++) acc += p0_l[k0 + k] * W1[(k0 + k) * H2 + j];
        p1part[h][j] = acc;
    }
    __syncthreads();
    if (t < H2) p1_l[t] = fmaxf(p1part[0][t] + p1part[1][t] + b1[t], 0.f);
    __syncthreads();

    {
        int c = t & 63, h = t >> 6;
        float acc = 0.f;
        int k0 = h * 32;
        for (int k = 0; k < 32; k++) acc += p1_l[k0 + k] * W2[(k0 + k) * H + c];
        p2part[h][c] = acc;
    }
    __syncthreads();
    if (t < H) p2_l[t] = fmaxf(((p2part[0][t] + p2part[1][t]) + (p2part[2][t] + p2part[3][t])) + b2[t], 0.f);
    __syncthreads();

    if (t < 64) {
        float v = p2_l[t] * Wo[t];
#pragma unroll
        for (int off = 32; off >= 1; off >>= 1) v += __shfl_xor(v, off, 64);
        if (t == 0) out[g] = v + bo[0];
    }
}

extern "C" void kernel_launch(void* const* d_in, const int* in_sizes, int n_in,
                              void* d_out, int out_size, void* d_ws, size_t ws_size,
                              hipStream_t stream) {
    const float* x       = (const float*)d_in[0];
    const int*   ei      = (const int*)d_in[1];
    const int*   batch   = (const int*)d_in[2];
    const float* conv1_W = (const float*)d_in[3];
    const float* conv1_b = (const float*)d_in[4];
    const float* bn1_g   = (const float*)d_in[5];
    const float* bn1_b   = (const float*)d_in[6];
    const float* ln_g    = (const float*)d_in[7];
    const float* ln_b    = (const float*)d_in[8];
    const float* prelu_a = (const float*)d_in[9];
    const float* gen_t   = (const float*)d_in[10];
    const float* mlp_W1  = (const float*)d_in[11];
    const float* mlp_b1  = (const float*)d_in[12];
    const float* mlp_bng = (const float*)d_in[13];
    const float* mlp_bnb = (const float*)d_in[14];
    const float* mlp_W2  = (const float*)d_in[15];
    const float* mlp_b2  = (const float*)d_in[16];
    const float* lin1_W  = (const float*)d_in[17];
    const float* lin1_b  = (const float*)d_in[18];
    const float* lin2_W  = (const float*)d_in[19];
    const float* lin2_b  = (const float*)d_in[20];
    const float* out_W   = (const float*)d_in[21];
    const float* out_b   = (const float*)d_in[22];
    float* out = (float*)d_out;

    float* ws   = (float*)d_ws;
    float* xc   = ws;                          // NND*H4
    float* u    = xc + (size_t)NND * H4;       // NND*H
    float* ua   = u + (size_t)NND * H;         // NND*H (t0 aliases)
    float* t0   = ua;
    float* dinv = ua + (size_t)NND * H;        // NND
    int* rowptr = (int*)(dinv + NND);          // NND+1
    int* next   = rowptr + (NND + 1);          // NND
    int* counts = next + NND;                  // NND
    int* bsum   = counts + NND;                // NB
    int* boff   = bsum + NB;                   // NB
    int* bcur   = boff + NB;                   // NXP
    int* gstart = bcur + NXP;                  // NG+1
    int* csr    = gstart + NG + 1;             // NE
    uintptr_t wb = (uintptr_t)(csr + NE);
    wb = (wb + 15) & ~(uintptr_t)15;
    _Float16* w1f = (_Float16*)wb;             // 3*8192 halves
    _Float16* w2f = w1f + 3 * 8192;            // 3*8192 halves
    _Float16* t0h = w2f + 3 * 8192;            // NND*H halves
    _Float16* u_h = t0h + (size_t)NND * H;     // NND*H halves
    uintptr_t eb = (uintptr_t)(u_h + (size_t)NND * H);
    eb = (eb + 15) & ~(uintptr_t)15;
    uint2* ebuf = (uint2*)eb;                  // NXP*BCAP uint2 (10.24 MB)
    // psum/pmax alias ebuf (ebuf dead after scatter; pooling runs at the end)
    float* psum_p = (float*)ebuf;              // NG*PC*H4
    float* pmax_p = psum_p + (size_t)NG * PC * H4;

    const int B = 256;
    const int gN   = (NND + B - 1) / B;
    const int gNH  = (NND * H) / B;
    const int gMLP = (NND + MT - 1) / MT;   // 782
    const int gE   = (NE + B - 1) / B;      // 4688
    const int gBK  = NXP * NBK;             // 5000

    // ---- CSR build (bucketized) + weight swizzle ----
    k_zero<<<gN, B, 0, stream>>>(counts, bcur);
    k_bucket<<<gE, B, 0, stream>>>(ei, bcur, ebuf);
    k_count_b<<<gBK, B, 0, stream>>>(bcur, ebuf, counts);
    k_scan1<<<NB, B, 0, stream>>>(counts, rowptr, bsum);
    k_scan2<<<1, B, 0, stream>>>(bsum, boff, rowptr);
    k_scan3<<<NB, B, 0, stream>>>(boff, counts, rowptr, next, dinv);
    k_scatter_b<<<gBK, B, 0, stream>>>(bcur, ebuf, next, csr);
    k_gbounds<<<2, 256, 0, stream>>>(batch, gstart);
    k_wswz<<<12, 256, 0, stream>>>(mlp_W1, mlp_W2, w1f, w2f);

    // ---- GCNConv + LN0/PReLU0 ----
    k_conv1<<<gNH, B, 0, stream>>>(x, conv1_W, t0, t0h);
    k_gcn<<<gNH, B, 0, stream>>>(rowptr, csr, t0, t0h, dinv, conv1_b, bn1_g, bn1_b,
                                 ln_g, ln_b, prelu_a, xc, u, u_h);

    // ---- DeepGCN layers ----
    for (int i = 0; i < 3; i++) {
        k_gen<<<gNH, B, 0, stream>>>(rowptr, csr, u, u_h, gen_t, i, ua);
        int do_ln = (i < 2) ? 1 : 0;
        k_mlp<<<gMLP, B, 0, stream>>>(ua,
                                      w1f + (size_t)i * 8192, w2f + (size_t)i * 8192,
                                      mlp_b1 + i * H2,
                                      mlp_bng + i * H2, mlp_bnb + i * H2,
                                      mlp_b2 + i * H,
                                      xc, i,
                                      ln_g + (i + 1) * H, ln_b + (i + 1) * H,
                                      prelu_a + (i + 1) * H, u, u_h, do_ln);
    }

    // ---- pooling + readout (psum/pmax alias dead ebuf) ----
    k_pool1<<<NG * PC, B, 0, stream>>>(xc, gstart, psum_p, pmax_p);
    k_readout<<<NG, B, 0, stream>>>(psum_p, pmax_p, gstart,
                                    lin1_W, lin1_b, lin2_W, lin2_b, out_W, out_b, out);
}

// Round 9
// 541.730 us; speedup vs baseline: 1.0191x; 1.0191x over previous
//
#include <hip/hip_runtime.h>
#include <math.h>

#define NND 50000
#define NE  1200000
#define NG  256
#define H   64
#define H2  128
#define H4  256
#define H8  512
#define FIN 5
#define EPS_BN 1e-5f
#define EPS_MSG 1e-7f
#define NB 196          // ceil(NND/256)
#define NXP 8           // XCD partitions
#define DPART 6250      // NND / NXP
#define ECH 4688        // ceil(NE/256)
#define PC 8            // pool chunks per graph
#define MT 64           // nodes per layer block

typedef _Float16 half8 __attribute__((ext_vector_type(8)));
typedef _Float16 half4 __attribute__((ext_vector_type(4)));
typedef float floatx4 __attribute__((ext_vector_type(4)));

// ---------------- setup: zero counts + gbounds + weight swizzle ----------------

__global__ void k_setup(const int* __restrict__ batch, int* counts, int* __restrict__ gstart,
                        const float* __restrict__ W1, const float* __restrict__ W2,
                        _Float16* __restrict__ w1f, _Float16* __restrict__ w2f) {
    int b = blockIdx.x, t = threadIdx.x;
    if (b < NB) {
        int n = b * 256 + t;
        if (n < NND) counts[n] = 0;
        return;
    }
    if (b == NB || b == NB + 1) {
        int g = (b - NB) * 256 + t;
        if (g > NG) return;
        int lo = 0, hi = NND;
        while (lo < hi) { int mid = (lo + hi) >> 1; if (batch[mid] < g) lo = mid + 1; else hi = mid; }
        gstart[g] = lo;
        return;
    }
    // weight swizzle: 12 blocks, 3072 threads
    int tt = (b - NB - 2) * 256 + t;
    if (tt >= 3 * 16 * 64) return;
    int lane = tt & 63, fr = (tt >> 6) & 15, l = tt >> 10;
    {
        int jt = fr >> 1, kf = fr & 1;
        int j = jt * 16 + (lane & 15);
        int k0 = kf * 32 + (lane >> 4) * 8;
#pragma unroll
        for (int i = 0; i < 8; i++)
            w1f[(((size_t)l * 16 + jt * 2 + kf) * 64 + lane) * 8 + i] =
                (_Float16)W1[(size_t)l * H * H2 + (k0 + i) * H2 + j];
    }
    {
        int ct = fr >> 2, k2f = fr & 3;
        int c = ct * 16 + (lane & 15);
        int k0 = k2f * 32 + (lane >> 4) * 8;
#pragma unroll
        for (int i = 0; i < 8; i++)
            w2f[(((size_t)l * 16 + ct * 4 + k2f) * 64 + lane) * 8 + i] =
                (_Float16)W2[(size_t)l * H2 * H + (k0 + i) * H + c];
    }
}

// ---------------- CSR build (by dst), XCD-partitioned (round-7 proven) ----------------

__global__ void k_count_p(const int* __restrict__ ei, int* counts) {
    int b = blockIdx.x;
    int g = b & (NXP - 1);
    int e = (b >> 3) * 256 + threadIdx.x;
    if (e >= NE) return;
    int d = ei[NE + e];
    if ((unsigned)(d - g * DPART) < (unsigned)DPART) atomicAdd(&counts[d], 1);
}

__global__ void k_scan1(const int* __restrict__ counts, int* __restrict__ rowptr,
                        int* __restrict__ bsum) {
    __shared__ int wsum[4];
    int b = blockIdx.x, t = threadIdx.x;
    int i = b * 256 + t;
    int v = (i < NND) ? counts[i] : 0;
    int lane = t & 63, wid = t >> 6;
    int sv = v;
#pragma unroll
    for (int off = 1; off < 64; off <<= 1) {
        int x = __shfl_up(sv, off, 64);
        if (lane >= off) sv += x;
    }
    if (lane == 63) wsum[wid] = sv;
    __syncthreads();
    int woff = 0;
    for (int w = 0; w < wid; w++) woff += wsum[w];
    int inc = woff + sv;
    if (i < NND) rowptr[i + 1] = inc;
    if (t == 255) bsum[b] = inc;
}

__global__ void k_scan2(const int* __restrict__ bsum, int* __restrict__ boff,
                        int* __restrict__ rowptr) {
    __shared__ int wsum[4];
    int t = threadIdx.x;
    int v = (t < NB) ? bsum[t] : 0;
    int lane = t & 63, wid = t >> 6;
    int sv = v;
#pragma unroll
    for (int off = 1; off < 64; off <<= 1) {
        int x = __shfl_up(sv, off, 64);
        if (lane >= off) sv += x;
    }
    if (lane == 63) wsum[wid] = sv;
    __syncthreads();
    int woff = 0;
    for (int w = 0; w < wid; w++) woff += wsum[w];
    if (t < NB) boff[t] = woff + sv - v;
    if (t == 0) rowptr[0] = 0;
}

__global__ void k_scan3(const int* __restrict__ boff, const int* __restrict__ counts,
                        int* __restrict__ rowptr, int* __restrict__ next,
                        float* __restrict__ dinv) {
    int i = blockIdx.x * 256 + threadIdx.x;
    if (i >= NND) return;
    int r = rowptr[i + 1] + boff[i >> 8];
    rowptr[i + 1] = r;
    next[i] = r - counts[i];
    dinv[i] = rsqrtf((float)counts[i] + 1.0f);
}

__global__ void k_scatter_p(const int* __restrict__ ei, int* next, int* csr) {
    int b = blockIdx.x;
    int g = b & (NXP - 1);
    int e = (b >> 3) * 256 + threadIdx.x;
    if (e >= NE) return;
    int d = ei[NE + e];
    if ((unsigned)(d - g * DPART) < (unsigned)DPART) {
        int pos = atomicAdd(&next[d], 1);
        csr[pos] = ei[e];
    }
}

// ---------------- GCNConv (f32 float4 gather, round-6 proven) ----------------

__global__ void k_conv1(const float* __restrict__ x, const float* __restrict__ W,
                        float* __restrict__ t0) {
    int tid = blockIdx.x * blockDim.x + threadIdx.x;
    if (tid >= NND * H) return;
    int n = tid >> 6, c = tid & 63;
    float acc = 0.f;
#pragma unroll
    for (int k = 0; k < FIN; k++) acc += x[n * FIN + k] * W[k * H + c];
    t0[n * H + c] = acc;
}

__global__ void k_gcn(const int* __restrict__ rowptr, const int* __restrict__ csr,
                      const float* __restrict__ t0, const float* __restrict__ dinv,
                      const float* __restrict__ cb, const float* __restrict__ bg,
                      const float* __restrict__ bb,
                      const float* __restrict__ lg, const float* __restrict__ lb,
                      const float* __restrict__ pa,
                      float* __restrict__ xc, float* __restrict__ u) {
    int d = (blockIdx.x * blockDim.x + threadIdx.x) >> 6;
    int lane = threadIdx.x & 63;
    if (d >= NND) return;
    int q = lane & 15, eg = lane >> 4;
    int beg = rowptr[d], end = rowptr[d + 1];
    float4 acc = {0.f, 0.f, 0.f, 0.f};
    for (int i0 = beg; i0 < end; i0 += 64) {
        int idx = i0 + lane;
        int csrv = 0; float dvv = 0.f;
        if (idx < end) { csrv = csr[idx]; dvv = dinv[csrv]; }
        int chunk = min(64, end - i0);
        for (int j = 0; j < chunk; j += 4) {
            int e_rel = j + eg;
            int s  = __shfl(csrv, e_rel, 64);
            float dv = __shfl(dvv, e_rel, 64);
            if (i0 + e_rel < end) {
                float4 tv = *(const float4*)&t0[s * H + 4 * q];
                acc.x += tv.x * dv; acc.y += tv.y * dv;
                acc.z += tv.z * dv; acc.w += tv.w * dv;
            }
        }
    }
#pragma unroll
    for (int off = 16; off <= 32; off <<= 1) {
        acc.x += __shfl_xor(acc.x, off, 64);
        acc.y += __shfl_xor(acc.y, off, 64);
        acc.z += __shfl_xor(acc.z, off, 64);
        acc.w += __shfl_xor(acc.w, off, 64);
    }
    if (eg == 0) {
        float dd = dinv[d];
        float4 ts = *(const float4*)&t0[d * H + 4 * q];
        float4 cbv = *(const float4*)&cb[4 * q];
        float4 bgv = *(const float4*)&bg[4 * q];
        float4 bbv = *(const float4*)&bb[4 * q];
        float bns = rsqrtf(1.f + EPS_BN);
        float4 x0;
        x0.x = fmaxf((acc.x * dd + ts.x * dd * dd + cbv.x) * (bgv.x * bns) + bbv.x, 0.f);
        x0.y = fmaxf((acc.y * dd + ts.y * dd * dd + cbv.y) * (bgv.y * bns) + bbv.y, 0.f);
        x0.z = fmaxf((acc.z * dd + ts.z * dd * dd + cbv.z) * (bgv.z * bns) + bbv.z, 0.f);
        x0.w = fmaxf((acc.w * dd + ts.w * dd * dd + cbv.w) * (bgv.w * bns) + bbv.w, 0.f);
        *(float4*)&xc[(size_t)d * H4 + 4 * q] = x0;
        float sum = (x0.x + x0.y) + (x0.z + x0.w);
        float sq  = (x0.x * x0.x + x0.y * x0.y) + (x0.z * x0.z + x0.w * x0.w);
#pragma unroll
        for (int off = 1; off <= 8; off <<= 1) {
            sum += __shfl_xor(sum, off, 64);
            sq  += __shfl_xor(sq,  off, 64);
        }
        float mu  = sum * (1.f / H);
        float var = sq * (1.f / H) - mu * mu;
        float rs = rsqrtf(var + EPS_BN);
        float4 lgv = *(const float4*)&lg[4 * q];
        float4 lbv = *(const float4*)&lb[4 * q];
        float4 pav = *(const float4*)&pa[4 * q];
        float4 y;
        y.x = (x0.x - mu) * rs * lgv.x + lbv.x;
        y.y = (x0.y - mu) * rs * lgv.y + lbv.y;
        y.z = (x0.z - mu) * rs * lgv.z + lbv.z;
        y.w = (x0.w - mu) * rs * lgv.w + lbv.w;
        y.x = (y.x >= 0.f) ? y.x : pav.x * y.x;
        y.y = (y.y >= 0.f) ? y.y : pav.y * y.y;
        y.z = (y.z >= 0.f) ? y.z : pav.z * y.z;
        y.w = (y.w >= 0.f) ? y.w : pav.w * y.w;
        *(float4*)&u[d * H + 4 * q] = y;
    }
}

// ---------------- fused DeepGCN layer: GEN gather + MFMA MLP, barrier-free ----------------
// 64 nodes/block, wave w owns nodes [nb+16w, nb+16w+16) end-to-end.
// Gather (f32 float4, 4 edges/instr) -> ua -> f16 A-frags in LDS (intra-wave)
// -> GEMM1 -> BN/ReLU -> a2 -> GEMM2 -> residual -> optional LN/PReLU -> u_out.
// u double-buffered across layers (fusion makes in/out of u racy otherwise).

__global__ void __launch_bounds__(256)
k_layer(const int* __restrict__ rowptr, const int* __restrict__ csr,
        const float* __restrict__ u_in, const float* __restrict__ tptr, int li,
        const _Float16* __restrict__ w1f, const _Float16* __restrict__ w2f,
        const float* __restrict__ b1,
        const float* __restrict__ bng, const float* __restrict__ bnb,
        const float* __restrict__ b2,
        float* __restrict__ xc, int slice,
        const float* __restrict__ lg, const float* __restrict__ lb,
        const float* __restrict__ pa, float* __restrict__ u_out, int do_ln) {
    __shared__ _Float16 a1[4][2][64][8];   // 8 KB  [wave][kf][lane][i]
    __shared__ _Float16 a2[4][4][64][8];   // 16 KB [wave][k2f][lane][i]
    int t = threadIdx.x;
    int w = t >> 6, l = t & 63;
    int nb = blockIdx.x * MT;
    int q = l & 15, eg = l >> 4;
    float tt = tptr[li];
    bool wvalid = (nb + 16 * w) < NND;

    // ---- gather phase: GENConv softmax-agg for this wave's 16 nodes ----
    for (int m = 0; m < 16; m++) {
        int d = nb + 16 * w + m;
        float4 o = {0.f, 0.f, 0.f, 0.f};
        if (d < NND) {
            int beg = rowptr[d], end = rowptr[d + 1];
            float4 s4 = {0.f, 0.f, 0.f, 0.f}, n4 = {0.f, 0.f, 0.f, 0.f};
            for (int i0 = beg; i0 < end; i0 += 64) {
                int idx = i0 + l;
                int csrv = (idx < end) ? csr[idx] : 0;
                int chunk = min(64, end - i0);
                for (int j = 0; j < chunk; j += 4) {
                    int e_rel = j + eg;
                    int s = __shfl(csrv, e_rel, 64);
                    if (i0 + e_rel < end) {
                        float4 uv = *(const float4*)&u_in[s * H + 4 * q];
                        float m0 = fmaxf(uv.x, 0.f) + EPS_MSG;
                        float m1 = fmaxf(uv.y, 0.f) + EPS_MSG;
                        float m2 = fmaxf(uv.z, 0.f) + EPS_MSG;
                        float m3 = fmaxf(uv.w, 0.f) + EPS_MSG;
                        float e0 = __expf(m0 * tt - 8.f);
                        float e1 = __expf(m1 * tt - 8.f);
                        float e2 = __expf(m2 * tt - 8.f);
                        float e3 = __expf(m3 * tt - 8.f);
                        s4.x += e0; s4.y += e1; s4.z += e2; s4.w += e3;
                        n4.x += m0 * e0; n4.y += m1 * e1; n4.z += m2 * e2; n4.w += m3 * e3;
                    }
                }
            }
#pragma unroll
            for (int off = 16; off <= 32; off <<= 1) {
                s4.x += __shfl_xor(s4.x, off, 64); s4.y += __shfl_xor(s4.y, off, 64);
                s4.z += __shfl_xor(s4.z, off, 64); s4.w += __shfl_xor(s4.w, off, 64);
                n4.x += __shfl_xor(n4.x, off, 64); n4.y += __shfl_xor(n4.y, off, 64);
                n4.z += __shfl_xor(n4.z, off, 64); n4.w += __shfl_xor(n4.w, off, 64);
            }
            float4 us = *(const float4*)&u_in[d * H + 4 * q];
            o.x = us.x + ((s4.x > 0.f) ? n4.x / s4.x : 0.f);
            o.y = us.y + ((s4.y > 0.f) ? n4.y / s4.y : 0.f);
            o.z = us.z + ((s4.z > 0.f) ? n4.z / s4.z : 0.f);
            o.w = us.w + ((s4.w > 0.f) ? n4.w / s4.w : 0.f);
        }
        // write ua(node m, channels 4q..4q+3) into A-frag layout (intra-wave):
        // (m, k=4q+j) -> a1[w][q>>3][m + 16*((q>>1)&3)][(q&1)*4 + j]
        if (eg == 0) {
            half4 h = {(_Float16)o.x, (_Float16)o.y, (_Float16)o.z, (_Float16)o.w};
            *(half4*)&a1[w][q >> 3][m + 16 * ((q >> 1) & 3)][(q & 1) * 4] = h;
        }
    }

    // ---- GEMM1: z1[16n x 128j] (intra-wave LDS; no barrier) ----
    int c_in = q, quad = eg;
    floatx4 acc[8];
#pragma unroll
    for (int jt = 0; jt < 8; jt++) acc[jt] = (floatx4){0.f, 0.f, 0.f, 0.f};
    half8 af0 = *(half8*)&a1[w][0][l][0];
    half8 af1 = *(half8*)&a1[w][1][l][0];
#pragma unroll
    for (int jt = 0; jt < 8; jt++) {
        half8 bf0 = *(const half8*)&w1f[((size_t)(jt * 2 + 0) * 64 + l) * 8];
        half8 bf1 = *(const half8*)&w1f[((size_t)(jt * 2 + 1) * 64 + l) * 8];
        acc[jt] = __builtin_amdgcn_mfma_f32_16x16x32_f16(af0, bf0, acc[jt], 0, 0, 0);
        acc[jt] = __builtin_amdgcn_mfma_f32_16x16x32_f16(af1, bf1, acc[jt], 0, 0, 0);
    }

    // ---- epilogue1: bias+BN+ReLU -> a2 (A-frag layout) ----
    {
        float bns = rsqrtf(1.f + EPS_BN);
#pragma unroll
        for (int jt = 0; jt < 8; jt++) {
            int j = jt * 16 + c_in;
            float b1v = b1[j], bsv = bng[j] * bns, bbv = bnb[j];
            int kf2 = jt >> 1;
            int lp = 16 * ((2 * jt + (c_in >> 3)) & 3);
            int ii = c_in & 7;
#pragma unroll
            for (int reg = 0; reg < 4; reg++) {
                float z = fmaxf((acc[jt][reg] + b1v) * bsv + bbv, 0.f);
                a2[w][kf2][quad * 4 + reg + lp][ii] = (_Float16)z;
            }
        }
    }

    // ---- GEMM2: z2[16n x 64c] ----
    floatx4 acc2[4];
#pragma unroll
    for (int ct = 0; ct < 4; ct++) acc2[ct] = (floatx4){0.f, 0.f, 0.f, 0.f};
    half8 a2f[4];
#pragma unroll
    for (int k2f = 0; k2f < 4; k2f++) a2f[k2f] = *(half8*)&a2[w][k2f][l][0];
#pragma unroll
    for (int ct = 0; ct < 4; ct++) {
#pragma unroll
        for (int k2f = 0; k2f < 4; k2f++) {
            half8 bfr = *(const half8*)&w2f[((size_t)(ct * 4 + k2f) * 64 + l) * 8];
            acc2[ct] = __builtin_amdgcn_mfma_f32_16x16x32_f16(a2f[k2f], bfr, acc2[ct], 0, 0, 0);
        }
    }

    // ---- epilogue2: residual + optional LN/PReLU ----
    float vv[4][4];
#pragma unroll
    for (int ct = 0; ct < 4; ct++) {
        int c = ct * 16 + c_in;
        float b2v = b2[c];
#pragma unroll
        for (int reg = 0; reg < 4; reg++) {
            int node = nb + 16 * w + quad * 4 + reg;
            float v = 0.f;
            if (wvalid) {
                v = xc[(size_t)node * H4 + slice * H + c] + acc2[ct][reg] + b2v;
                xc[(size_t)node * H4 + (slice + 1) * H + c] = v;
            }
            vv[ct][reg] = v;
        }
    }
    if (do_ln) {
#pragma unroll
        for (int reg = 0; reg < 4; reg++) {
            float s = (vv[0][reg] + vv[1][reg]) + (vv[2][reg] + vv[3][reg]);
            float qq = (vv[0][reg] * vv[0][reg] + vv[1][reg] * vv[1][reg]) +
                       (vv[2][reg] * vv[2][reg] + vv[3][reg] * vv[3][reg]);
#pragma unroll
            for (int off = 1; off <= 8; off <<= 1) {
                s += __shfl_xor(s, off, 64);
                qq += __shfl_xor(qq, off, 64);
            }
            float mu = s * (1.f / H);
            float var = qq * (1.f / H) - mu * mu;
            float rs = rsqrtf(var + EPS_BN);
            int node = nb + 16 * w + quad * 4 + reg;
#pragma unroll
            for (int ct = 0; ct < 4; ct++) {
                int c = ct * 16 + c_in;
                float y = (vv[ct][reg] - mu) * rs * lg[c] + lb[c];
                y = (y >= 0.f) ? y : pa[c] * y;
                if (wvalid) u_out[node * H + c] = y;
            }
        }
    }
}

// ---------------- pooling + readout ----------------

__global__ void __launch_bounds__(256)
k_pool1(const float* __restrict__ xc, const int* __restrict__ gstart,
        float* __restrict__ psum_p, float* __restrict__ pmax_p) {
    __shared__ float4 ssum[256];
    __shared__ float4 smax[256];
    int b = blockIdx.x;
    int g = b >> 3, k = b & (PC - 1);
    int t = threadIdx.x;
    int start = gstart[g], end = gstart[g + 1];
    int len = end - start;
    int c0 = start + (len * k) / PC;
    int c1 = start + (len * (k + 1)) / PC;
    int q = t & 63, sub = t >> 6;
    float4 sum = {0.f, 0.f, 0.f, 0.f};
    float4 mx = {-INFINITY, -INFINITY, -INFINITY, -INFINITY};
    for (int n = c0 + sub; n < c1; n += 4) {
        float4 v = *(const float4*)&xc[(size_t)n * H4 + 4 * q];
        sum.x += v.x; sum.y += v.y; sum.z += v.z; sum.w += v.w;
        mx.x = fmaxf(mx.x, v.x); mx.y = fmaxf(mx.y, v.y);
        mx.z = fmaxf(mx.z, v.z); mx.w = fmaxf(mx.w, v.w);
    }
    ssum[t] = sum; smax[t] = mx;
    __syncthreads();
    if (t < 64) {
        float4 s0 = ssum[t], s1 = ssum[t + 64], s2 = ssum[t + 128], s3 = ssum[t + 192];
        float4 m0 = smax[t], m1 = smax[t + 64], m2 = smax[t + 128], m3 = smax[t + 192];
        float4 S, M;
        S.x = (s0.x + s1.x) + (s2.x + s3.x);
        S.y = (s0.y + s1.y) + (s2.y + s3.y);
        S.z = (s0.z + s1.z) + (s2.z + s3.z);
        S.w = (s0.w + s1.w) + (s2.w + s3.w);
        M.x = fmaxf(fmaxf(m0.x, m1.x), fmaxf(m2.x, m3.x));
        M.y = fmaxf(fmaxf(m0.y, m1.y), fmaxf(m2.y, m3.y));
        M.z = fmaxf(fmaxf(m0.z, m1.z), fmaxf(m2.z, m3.z));
        M.w = fmaxf(fmaxf(m0.w, m1.w), fmaxf(m2.w, m3.w));
        *(float4*)&psum_p[(size_t)b * H4 + 4 * q] = S;
        *(float4*)&pmax_p[(size_t)b * H4 + 4 * q] = M;
    }
}

__global__ void __launch_bounds__(256)
k_readout(const float* __restrict__ psum_p, const float* __restrict__ pmax_p,
          const int* __restrict__ gstart,
          const float* __restrict__ W1, const float* __restrict__ b1,
          const float* __restrict__ W2, const float* __restrict__ b2,
          const float* __restrict__ Wo, const float* __restrict__ bo,
          float* __restrict__ out) {
    __shared__ float p0_l[H8];
    __shared__ float p1part[2][H2];
    __shared__ float p1_l[H2];
    __shared__ float p2part[4][H];
    __shared__ float p2_l[H];
    int g = blockIdx.x;
    int t = threadIdx.x;

    {
        float s = 0.f, m = -INFINITY;
#pragma unroll
        for (int k = 0; k < PC; k++) {
            s += psum_p[(size_t)(g * PC + k) * H4 + t];
            m = fmaxf(m, pmax_p[(size_t)(g * PC + k) * H4 + t]);
        }
        int cnt = gstart[g + 1] - gstart[g];
        p0_l[t] = s / fmaxf((float)cnt, 1.f);
        p0_l[H4 + t] = (cnt > 0) ? m : 0.f;
    }
    __syncthreads();

    {
        int j = t & 127, h = t >> 7;
        float acc = 0.f;
        int k0 = h * 256;
        for (int k = 0; k < 256; k++) acc += p0_l[k0 + k] * W1[(k0 + k) * H2 + j];
        p1part[h][j] = acc;
    }
    __syncthreads();
    if (t < H2) p1_l[t] = fmaxf(p1part[0][t] + p1part[1][t] + b1[t], 0.f);
    __syncthreads();

    {
        int c = t & 63, h = t >> 6;
        float acc = 0.f;
        int k0 = h * 32;
        for (int k = 0; k < 32; k++) acc += p1_l[k0 + k] * W2[(k0 + k) * H + c];
        p2part[h][c] = acc;
    }
    __syncthreads();
    if (t < H) p2_l[t] = fmaxf(((p2part[0][t] + p2part[1][t]) + (p2part[2][t] + p2part[3][t])) + b2[t], 0.f);
    __syncthreads();

    if (t < 64) {
        float v = p2_l[t] * Wo[t];
#pragma unroll
        for (int off = 32; off >= 1; off >>= 1) v += __shfl_xor(v, off, 64);
        if (t == 0) out[g] = v + bo[0];
    }
}

extern "C" void kernel_launch(void* const* d_in, const int* in_sizes, int n_in,
                              void* d_out, int out_size, void* d_ws, size_t ws_size,
                              hipStream_t stream) {
    const float* x       = (const float*)d_in[0];
    const int*   ei      = (const int*)d_in[1];
    const int*   batch   = (const int*)d_in[2];
    const float* conv1_W = (const float*)d_in[3];
    const float* conv1_b = (const float*)d_in[4];
    const float* bn1_g   = (const float*)d_in[5];
    const float* bn1_b   = (const float*)d_in[6];
    const float* ln_g    = (const float*)d_in[7];
    const float* ln_b    = (const float*)d_in[8];
    const float* prelu_a = (const float*)d_in[9];
    const float* gen_t   = (const float*)d_in[10];
    const float* mlp_W1  = (const float*)d_in[11];
    const float* mlp_b1  = (const float*)d_in[12];
    const float* mlp_bng = (const float*)d_in[13];
    const float* mlp_bnb = (const float*)d_in[14];
    const float* mlp_W2  = (const float*)d_in[15];
    const float* mlp_b2  = (const float*)d_in[16];
    const float* lin1_W  = (const float*)d_in[17];
    const float* lin1_b  = (const float*)d_in[18];
    const float* lin2_W  = (const float*)d_in[19];
    const float* lin2_b  = (const float*)d_in[20];
    const float* out_W   = (const float*)d_in[21];
    const float* out_b   = (const float*)d_in[22];
    float* out = (float*)d_out;

    float* ws   = (float*)d_ws;
    float* xc   = ws;                          // NND*H4
    float* u0   = xc + (size_t)NND * H4;       // NND*H
    float* u1   = u0 + (size_t)NND * H;        // NND*H (t0 aliases; t0 dead before u1 written)
    float* t0   = u1;
    float* dinv = u1 + (size_t)NND * H;        // NND
    int* rowptr = (int*)(dinv + NND);          // NND+1
    int* next   = rowptr + (NND + 1);          // NND
    int* counts = next + NND;                  // NND
    int* bsum   = counts + NND;                // NB
    int* boff   = bsum + NB;                   // NB
    int* gstart = boff + NB;                   // NG+1
    int* csr    = gstart + NG + 1;             // NE
    uintptr_t wb = (uintptr_t)(csr + NE);
    wb = (wb + 15) & ~(uintptr_t)15;
    _Float16* w1f = (_Float16*)wb;             // 3*8192 halves
    _Float16* w2f = w1f + 3 * 8192;            // 3*8192 halves
    float* psum_p = (float*)(w2f + 3 * 8192);  // NG*PC*H4
    float* pmax_p = psum_p + (size_t)NG * PC * H4;

    const int B = 256;
    const int gNH  = (NND * H) / B;         // 12500
    const int gL   = (NND + MT - 1) / MT;   // 782
    const int gEP  = NXP * ECH;             // 37504

    // ---- setup (zero counts + gbounds + weight swizzle) + CSR build ----
    k_setup<<<NB + 2 + 12, B, 0, stream>>>(batch, counts, gstart, mlp_W1, mlp_W2, w1f, w2f);
    k_count_p<<<gEP, B, 0, stream>>>(ei, counts);
    k_scan1<<<NB, B, 0, stream>>>(counts, rowptr, bsum);
    k_scan2<<<1, B, 0, stream>>>(bsum, boff, rowptr);
    k_scan3<<<NB, B, 0, stream>>>(boff, counts, rowptr, next, dinv);
    k_scatter_p<<<gEP, B, 0, stream>>>(ei, next, csr);

    // ---- GCNConv + LN0/PReLU0 ----
    k_conv1<<<gNH, B, 0, stream>>>(x, conv1_W, t0);
    k_gcn<<<gNH, B, 0, stream>>>(rowptr, csr, t0, dinv, conv1_b, bn1_g, bn1_b,
                                 ln_g, ln_b, prelu_a, xc, u0);

    // ---- DeepGCN layers (fused gather+MLP; u ping-pong) ----
    float* uin = u0;
    float* uout = u1;
    for (int i = 0; i < 3; i++) {
        int do_ln = (i < 2) ? 1 : 0;
        k_layer<<<gL, B, 0, stream>>>(rowptr, csr, uin, gen_t, i,
                                      w1f + (size_t)i * 8192, w2f + (size_t)i * 8192,
                                      mlp_b1 + i * H2,
                                      mlp_bng + i * H2, mlp_bnb + i * H2,
                                      mlp_b2 + i * H,
                                      xc, i,
                                      ln_g + (i + 1) * H, ln_b + (i + 1) * H,
                                      prelu_a + (i + 1) * H, uout, do_ln);
        float* tmp = uin; uin = uout; uout = tmp;
    }

    // ---- pooling + readout ----
    k_pool1<<<NG * PC, B, 0, stream>>>(xc, gstart, psum_p, pmax_p);
    k_readout<<<NG, B, 0, stream>>>(psum_p, pmax_p, gstart,
                                    lin1_W, lin1_b, lin2_W, lin2_b, out_W, out_b, out);
}

// Round 10
// 526.054 us; speedup vs baseline: 1.0494x; 1.0298x over previous
//
#include <hip/hip_runtime.h>
#include <math.h>

#define NND 50000
#define NE  1200000
#define NG  256
#define H   64
#define H2  128
#define H4  256
#define H8  512
#define FIN 5
#define EPS_BN 1e-5f
#define EPS_MSG 1e-7f
#define NB 196          // ceil(NND/256)
#define NXP 8           // buckets (XCD affinity via blockIdx round-robin)
#define DPART 6250      // NND / NXP
#define PC 8            // pool chunks per graph
#define MT 64           // nodes per mlp block
#define BCAP 160000     // bucket capacity (150000 expected, 27 sigma margin)
#define NBK 625         // BCAP / 256

typedef _Float16 half8 __attribute__((ext_vector_type(8)));
typedef float floatx4 __attribute__((ext_vector_type(4)));

// ---------------- setup: zero counts/bcur + gbounds + weight swizzle ----------------

__global__ void k_setup(const int* __restrict__ batch, int* counts, int* bcur,
                        int* __restrict__ gstart,
                        const float* __restrict__ W1, const float* __restrict__ W2,
                        _Float16* __restrict__ w1f, _Float16* __restrict__ w2f) {
    int b = blockIdx.x, t = threadIdx.x;
    if (b < NB) {
        int n = b * 256 + t;
        if (n < NND) counts[n] = 0;
        return;
    }
    if (b == NB || b == NB + 1) {
        if (b == NB + 1 && t < NXP) bcur[t] = 0;
        int g = (b - NB) * 256 + t;
        if (g > NG) return;
        int lo = 0, hi = NND;
        while (lo < hi) { int mid = (lo + hi) >> 1; if (batch[mid] < g) lo = mid + 1; else hi = mid; }
        gstart[g] = lo;
        return;
    }
    int tt = (b - NB - 2) * 256 + t;
    if (tt >= 3 * 16 * 64) return;
    int lane = tt & 63, fr = (tt >> 6) & 15, l = tt >> 10;
    {
        int jt = fr >> 1, kf = fr & 1;
        int j = jt * 16 + (lane & 15);
        int k0 = kf * 32 + (lane >> 4) * 8;
#pragma unroll
        for (int i = 0; i < 8; i++)
            w1f[(((size_t)l * 16 + jt * 2 + kf) * 64 + lane) * 8 + i] =
                (_Float16)W1[(size_t)l * H * H2 + (k0 + i) * H2 + j];
    }
    {
        int ct = fr >> 2, k2f = fr & 3;
        int c = ct * 16 + (lane & 15);
        int k0 = k2f * 32 + (lane >> 4) * 8;
#pragma unroll
        for (int i = 0; i < 8; i++)
            w2f[(((size_t)l * 16 + ct * 4 + k2f) * 64 + lane) * 8 + i] =
                (_Float16)W2[(size_t)l * H2 * H + (k0 + i) * H + c];
    }
}

// ---------------- CSR build: bucket (1 pass) -> count -> scan -> scatter ----------------

__global__ void k_bucket(const int* __restrict__ ei, int* bcur, uint2* __restrict__ ebuf) {
    __shared__ int lcnt[NXP];
    __shared__ int lbase[NXP];
    int t = threadIdx.x;
    int e = blockIdx.x * 256 + t;
    if (t < NXP) lcnt[t] = 0;
    __syncthreads();
    int s = 0, d = 0, bkt = 0, my = 0;
    bool v = e < NE;
    if (v) {
        s = ei[e]; d = ei[NE + e];
        bkt = d / DPART;
        my = atomicAdd(&lcnt[bkt], 1);
    }
    __syncthreads();
    if (t < NXP) lbase[t] = atomicAdd(&bcur[t], lcnt[t]);
    __syncthreads();
    if (v) {
        int pos = lbase[bkt] + my;
        if (pos < BCAP) ebuf[(size_t)bkt * BCAP + pos] = make_uint2((unsigned)s, (unsigned)d);
    }
}

// grid 8*NBK; block b -> bucket b&7: atomics confined to one 25KB counts slice
__global__ void k_count_b(const int* __restrict__ bcur, const uint2* __restrict__ ebuf,
                          int* counts) {
    int b = blockIdx.x;
    int bkt = b & (NXP - 1);
    int i = (b >> 3) * 256 + threadIdx.x;
    if (i >= bcur[bkt]) return;
    uint2 ed = ebuf[(size_t)bkt * BCAP + i];
    atomicAdd(&counts[ed.y], 1);
}

__global__ void k_scan1(const int* __restrict__ counts, int* __restrict__ rowptr,
                        int* __restrict__ bsum) {
    __shared__ int wsum[4];
    int b = blockIdx.x, t = threadIdx.x;
    int i = b * 256 + t;
    int v = (i < NND) ? counts[i] : 0;
    int lane = t & 63, wid = t >> 6;
    int sv = v;
#pragma unroll
    for (int off = 1; off < 64; off <<= 1) {
        int x = __shfl_up(sv, off, 64);
        if (lane >= off) sv += x;
    }
    if (lane == 63) wsum[wid] = sv;
    __syncthreads();
    int woff = 0;
    for (int w = 0; w < wid; w++) woff += wsum[w];
    int inc = woff + sv;
    if (i < NND) rowptr[i + 1] = inc;
    if (t == 255) bsum[b] = inc;
}

__global__ void k_scan2(const int* __restrict__ bsum, int* __restrict__ boff,
                        int* __restrict__ rowptr) {
    __shared__ int wsum[4];
    int t = threadIdx.x;
    int v = (t < NB) ? bsum[t] : 0;
    int lane = t & 63, wid = t >> 6;
    int sv = v;
#pragma unroll
    for (int off = 1; off < 64; off <<= 1) {
        int x = __shfl_up(sv, off, 64);
        if (lane >= off) sv += x;
    }
    if (lane == 63) wsum[wid] = sv;
    __syncthreads();
    int woff = 0;
    for (int w = 0; w < wid; w++) woff += wsum[w];
    if (t < NB) boff[t] = woff + sv - v;
    if (t == 0) rowptr[0] = 0;
}

__global__ void k_scan3(const int* __restrict__ boff, const int* __restrict__ counts,
                        int* __restrict__ rowptr, int* __restrict__ next,
                        float* __restrict__ dinv) {
    int i = blockIdx.x * 256 + threadIdx.x;
    if (i >= NND) return;
    int r = rowptr[i + 1] + boff[i >> 8];
    rowptr[i + 1] = r;
    next[i] = r - counts[i];
    dinv[i] = rsqrtf((float)counts[i] + 1.0f);
}

// csr writes confined to one ~600KB contiguous region per bucket (L2-resident)
__global__ void k_scatter_b(const int* __restrict__ bcur, const uint2* __restrict__ ebuf,
                            int* next, int* __restrict__ csr) {
    int b = blockIdx.x;
    int bkt = b & (NXP - 1);
    int i = (b >> 3) * 256 + threadIdx.x;
    if (i >= bcur[bkt]) return;
    uint2 ed = ebuf[(size_t)bkt * BCAP + i];
    int pos = atomicAdd(&next[ed.y], 1);
    csr[pos] = (int)ed.x;
}

// ---------------- GCNConv (f32 float4 gather + BN + ReLU + LN0 + PReLU0) ----------------

__global__ void k_conv1(const float* __restrict__ x, const float* __restrict__ W,
                        float* __restrict__ t0) {
    int tid = blockIdx.x * blockDim.x + threadIdx.x;
    if (tid >= NND * H) return;
    int n = tid >> 6, c = tid & 63;
    float acc = 0.f;
#pragma unroll
    for (int k = 0; k < FIN; k++) acc += x[n * FIN + k] * W[k * H + c];
    t0[n * H + c] = acc;
}

__global__ void k_gcn(const int* __restrict__ rowptr, const int* __restrict__ csr,
                      const float* __restrict__ t0, const float* __restrict__ dinv,
                      const float* __restrict__ cb, const float* __restrict__ bg,
                      const float* __restrict__ bb,
                      const float* __restrict__ lg, const float* __restrict__ lb,
                      const float* __restrict__ pa,
                      float* __restrict__ xc, float* __restrict__ u) {
    int d = (blockIdx.x * blockDim.x + threadIdx.x) >> 6;
    int lane = threadIdx.x & 63;
    if (d >= NND) return;
    int q = lane & 15, eg = lane >> 4;
    int beg = rowptr[d], end = rowptr[d + 1];
    float4 acc = {0.f, 0.f, 0.f, 0.f};
    for (int i0 = beg; i0 < end; i0 += 64) {
        int idx = i0 + lane;
        int csrv = 0; float dvv = 0.f;
        if (idx < end) { csrv = csr[idx]; dvv = dinv[csrv]; }
        int chunk = min(64, end - i0);
        for (int j = 0; j < chunk; j += 4) {
            int e_rel = j + eg;
            int s  = __shfl(csrv, e_rel, 64);
            float dv = __shfl(dvv, e_rel, 64);
            if (i0 + e_rel < end) {
                float4 tv = *(const float4*)&t0[s * H + 4 * q];
                acc.x += tv.x * dv; acc.y += tv.y * dv;
                acc.z += tv.z * dv; acc.w += tv.w * dv;
            }
        }
    }
#pragma unroll
    for (int off = 16; off <= 32; off <<= 1) {
        acc.x += __shfl_xor(acc.x, off, 64);
        acc.y += __shfl_xor(acc.y, off, 64);
        acc.z += __shfl_xor(acc.z, off, 64);
        acc.w += __shfl_xor(acc.w, off, 64);
    }
    if (eg == 0) {
        float dd = dinv[d];
        float4 ts = *(const float4*)&t0[d * H + 4 * q];
        float4 cbv = *(const float4*)&cb[4 * q];
        float4 bgv = *(const float4*)&bg[4 * q];
        float4 bbv = *(const float4*)&bb[4 * q];
        float bns = rsqrtf(1.f + EPS_BN);
        float4 x0;
        x0.x = fmaxf((acc.x * dd + ts.x * dd * dd + cbv.x) * (bgv.x * bns) + bbv.x, 0.f);
        x0.y = fmaxf((acc.y * dd + ts.y * dd * dd + cbv.y) * (bgv.y * bns) + bbv.y, 0.f);
        x0.z = fmaxf((acc.z * dd + ts.z * dd * dd + cbv.z) * (bgv.z * bns) + bbv.z, 0.f);
        x0.w = fmaxf((acc.w * dd + ts.w * dd * dd + cbv.w) * (bgv.w * bns) + bbv.w, 0.f);
        *(float4*)&xc[(size_t)d * H4 + 4 * q] = x0;
        float sum = (x0.x + x0.y) + (x0.z + x0.w);
        float sq  = (x0.x * x0.x + x0.y * x0.y) + (x0.z * x0.z + x0.w * x0.w);
#pragma unroll
        for (int off = 1; off <= 8; off <<= 1) {
            sum += __shfl_xor(sum, off, 64);
            sq  += __shfl_xor(sq,  off, 64);
        }
        float mu  = sum * (1.f / H);
        float var = sq * (1.f / H) - mu * mu;
        float rs = rsqrtf(var + EPS_BN);
        float4 lgv = *(const float4*)&lg[4 * q];
        float4 lbv = *(const float4*)&lb[4 * q];
        float4 pav = *(const float4*)&pa[4 * q];
        float4 y;
        y.x = (x0.x - mu) * rs * lgv.x + lbv.x;
        y.y = (x0.y - mu) * rs * lgv.y + lbv.y;
        y.z = (x0.z - mu) * rs * lgv.z + lbv.z;
        y.w = (x0.w - mu) * rs * lgv.w + lbv.w;
        y.x = (y.x >= 0.f) ? y.x : pav.x * y.x;
        y.y = (y.y >= 0.f) ? y.y : pav.y * y.y;
        y.z = (y.z >= 0.f) ? y.z : pav.z * y.z;
        y.w = (y.w >= 0.f) ? y.w : pav.w * y.w;
        *(float4*)&u[d * H + 4 * q] = y;
    }
}

// ---------------- GENConv softmax aggregation (f32 float4 gather, 1 wave/node) ----------------

__global__ void k_gen(const int* __restrict__ rowptr, const int* __restrict__ csr,
                      const float* __restrict__ u, const float* __restrict__ tptr,
                      int li, float* __restrict__ ua) {
    int d = (blockIdx.x * blockDim.x + threadIdx.x) >> 6;
    int lane = threadIdx.x & 63;
    if (d >= NND) return;
    int q = lane & 15, eg = lane >> 4;
    float t = tptr[li];
    int beg = rowptr[d], end = rowptr[d + 1];
    float4 s4 = {0.f, 0.f, 0.f, 0.f}, n4 = {0.f, 0.f, 0.f, 0.f};
    for (int i0 = beg; i0 < end; i0 += 64) {
        int idx = i0 + lane;
        int csrv = (idx < end) ? csr[idx] : 0;
        int chunk = min(64, end - i0);
        for (int j = 0; j < chunk; j += 4) {
            int e_rel = j + eg;
            int s = __shfl(csrv, e_rel, 64);
            if (i0 + e_rel < end) {
                float4 uv = *(const float4*)&u[s * H + 4 * q];
                float m0 = fmaxf(uv.x, 0.f) + EPS_MSG;
                float m1 = fmaxf(uv.y, 0.f) + EPS_MSG;
                float m2 = fmaxf(uv.z, 0.f) + EPS_MSG;
                float m3 = fmaxf(uv.w, 0.f) + EPS_MSG;
                float e0 = __expf(m0 * t - 8.f);
                float e1 = __expf(m1 * t - 8.f);
                float e2 = __expf(m2 * t - 8.f);
                float e3 = __expf(m3 * t - 8.f);
                s4.x += e0; s4.y += e1; s4.z += e2; s4.w += e3;
                n4.x += m0 * e0; n4.y += m1 * e1; n4.z += m2 * e2; n4.w += m3 * e3;
            }
        }
    }
#pragma unroll
    for (int off = 16; off <= 32; off <<= 1) {
        s4.x += __shfl_xor(s4.x, off, 64); s4.y += __shfl_xor(s4.y, off, 64);
        s4.z += __shfl_xor(s4.z, off, 64); s4.w += __shfl_xor(s4.w, off, 64);
        n4.x += __shfl_xor(n4.x, off, 64); n4.y += __shfl_xor(n4.y, off, 64);
        n4.z += __shfl_xor(n4.z, off, 64); n4.w += __shfl_xor(n4.w, off, 64);
    }
    if (eg == 0) {
        float4 us = *(const float4*)&u[d * H + 4 * q];
        float4 o;
        o.x = us.x + ((s4.x > 0.f) ? n4.x / s4.x : 0.f);
        o.y = us.y + ((s4.y > 0.f) ? n4.y / s4.y : 0.f);
        o.z = us.z + ((s4.z > 0.f) ? n4.z / s4.z : 0.f);
        o.w = us.w + ((s4.w > 0.f) ? n4.w / s4.w : 0.f);
        *(float4*)&ua[d * H + 4 * q] = o;
    }
}

// ---------------- fused MLP via MFMA (f16 inputs, f32 accumulate; round-7 proven) ----------------

__global__ void __launch_bounds__(256)
k_mlp(const float* __restrict__ ua,
      const _Float16* __restrict__ w1f, const _Float16* __restrict__ w2f,
      const float* __restrict__ b1,
      const float* __restrict__ bng, const float* __restrict__ bnb,
      const float* __restrict__ b2,
      float* __restrict__ xc, int slice,
      const float* __restrict__ lg, const float* __restrict__ lb,
      const float* __restrict__ pa, float* __restrict__ u_next, int do_ln) {
    __shared__ _Float16 a1[4][2][64][8];   // 8 KB
    __shared__ _Float16 a2[4][4][64][8];   // 16 KB
    int t = threadIdx.x;
    int w = t >> 6, l = t & 63;
    int nb = blockIdx.x * MT;
    int c_in = l & 15, quad = l >> 4;
    bool wvalid = (nb + 16 * w) < NND;

    {
        int n = t >> 2;
        int k0 = (t & 3) * 16;
        int gn = nb + n;
        float4 v0 = {0,0,0,0}, v1 = v0, v2 = v0, v3 = v0;
        if (gn < NND) {
            v0 = *(const float4*)&ua[gn * H + k0];
            v1 = *(const float4*)&ua[gn * H + k0 + 4];
            v2 = *(const float4*)&ua[gn * H + k0 + 8];
            v3 = *(const float4*)&ua[gn * H + k0 + 12];
        }
        int mt = n >> 4, kf = k0 >> 5, g0 = (k0 >> 3) & 3;
        half8 h0 = {(_Float16)v0.x, (_Float16)v0.y, (_Float16)v0.z, (_Float16)v0.w,
                    (_Float16)v1.x, (_Float16)v1.y, (_Float16)v1.z, (_Float16)v1.w};
        half8 h1 = {(_Float16)v2.x, (_Float16)v2.y, (_Float16)v2.z, (_Float16)v2.w,
                    (_Float16)v3.x, (_Float16)v3.y, (_Float16)v3.z, (_Float16)v3.w};
        *(half8*)&a1[mt][kf][(n & 15) + 16 * g0][0] = h0;
        *(half8*)&a1[mt][kf][(n & 15) + 16 * (g0 + 1)][0] = h1;
    }

    floatx4 acc[8];
#pragma unroll
    for (int jt = 0; jt < 8; jt++) acc[jt] = (floatx4){0.f, 0.f, 0.f, 0.f};
    half8 af0 = *(half8*)&a1[w][0][l][0];
    half8 af1 = *(half8*)&a1[w][1][l][0];
#pragma unroll
    for (int jt = 0; jt < 8; jt++) {
        half8 bf0 = *(const half8*)&w1f[((size_t)(jt * 2 + 0) * 64 + l) * 8];
        half8 bf1 = *(const half8*)&w1f[((size_t)(jt * 2 + 1) * 64 + l) * 8];
        acc[jt] = __builtin_amdgcn_mfma_f32_16x16x32_f16(af0, bf0, acc[jt], 0, 0, 0);
        acc[jt] = __builtin_amdgcn_mfma_f32_16x16x32_f16(af1, bf1, acc[jt], 0, 0, 0);
    }

    {
        float bns = rsqrtf(1.f + EPS_BN);
#pragma unroll
        for (int jt = 0; jt < 8; jt++) {
            int j = jt * 16 + c_in;
            float b1v = b1[j], bsv = bng[j] * bns, bbv = bnb[j];
            int kf2 = jt >> 1;
            int lp = 16 * ((2 * jt + (c_in >> 3)) & 3);
            int ii = c_in & 7;
#pragma unroll
            for (int reg = 0; reg < 4; reg++) {
                float z = fmaxf((acc[jt][reg] + b1v) * bsv + bbv, 0.f);
                a2[w][kf2][quad * 4 + reg + lp][ii] = (_Float16)z;
            }
        }
    }

    floatx4 acc2[4];
#pragma unroll
    for (int ct = 0; ct < 4; ct++) acc2[ct] = (floatx4){0.f, 0.f, 0.f, 0.f};
    half8 a2f[4];
#pragma unroll
    for (int k2f = 0; k2f < 4; k2f++) a2f[k2f] = *(half8*)&a2[w][k2f][l][0];
#pragma unroll
    for (int ct = 0; ct < 4; ct++) {
#pragma unroll
        for (int k2f = 0; k2f < 4; k2f++) {
            half8 bfr = *(const half8*)&w2f[((size_t)(ct * 4 + k2f) * 64 + l) * 8];
            acc2[ct] = __builtin_amdgcn_mfma_f32_16x16x32_f16(a2f[k2f], bfr, acc2[ct], 0, 0, 0);
        }
    }

    float vv[4][4];
#pragma unroll
    for (int ct = 0; ct < 4; ct++) {
        int c = ct * 16 + c_in;
        float b2v = b2[c];
#pragma unroll
        for (int reg = 0; reg < 4; reg++) {
            int node = nb + 16 * w + quad * 4 + reg;
            float v = 0.f;
            if (wvalid) {
                v = xc[(size_t)node * H4 + slice * H + c] + acc2[ct][reg] + b2v;
                xc[(size_t)node * H4 + (slice + 1) * H + c] = v;
            }
            vv[ct][reg] = v;
        }
    }
    if (do_ln) {
#pragma unroll
        for (int reg = 0; reg < 4; reg++) {
            float s = (vv[0][reg] + vv[1][reg]) + (vv[2][reg] + vv[3][reg]);
            float q = (vv[0][reg] * vv[0][reg] + vv[1][reg] * vv[1][reg]) +
                      (vv[2][reg] * vv[2][reg] + vv[3][reg] * vv[3][reg]);
#pragma unroll
            for (int off = 1; off <= 8; off <<= 1) {
                s += __shfl_xor(s, off, 64);
                q += __shfl_xor(q, off, 64);
            }
            float mu = s * (1.f / H);
            float var = q * (1.f / H) - mu * mu;
            float rs = rsqrtf(var + EPS_BN);
            int node = nb + 16 * w + quad * 4 + reg;
#pragma unroll
            for (int ct = 0; ct < 4; ct++) {
                int c = ct * 16 + c_in;
                float y = (vv[ct][reg] - mu) * rs * lg[c] + lb[c];
                y = (y >= 0.f) ? y : pa[c] * y;
                if (wvalid) u_next[node * H + c] = y;
            }
        }
    }
}

// ---------------- pooling + readout ----------------

__global__ void __launch_bounds__(256)
k_pool1(const float* __restrict__ xc, const int* __restrict__ gstart,
        float* __restrict__ psum_p, float* __restrict__ pmax_p) {
    __shared__ float4 ssum[256];
    __shared__ float4 smax[256];
    int b = blockIdx.x;
    int g = b >> 3, k = b & (PC - 1);
    int t = threadIdx.x;
    int start = gstart[g], end = gstart[g + 1];
    int len = end - start;
    int c0 = start + (len * k) / PC;
    int c1 = start + (len * (k + 1)) / PC;
    int q = t & 63, sub = t >> 6;
    float4 sum = {0.f, 0.f, 0.f, 0.f};
    float4 mx = {-INFINITY, -INFINITY, -INFINITY, -INFINITY};
    for (int n = c0 + sub; n < c1; n += 4) {
        float4 v = *(const float4*)&xc[(size_t)n * H4 + 4 * q];
        sum.x += v.x; sum.y += v.y; sum.z += v.z; sum.w += v.w;
        mx.x = fmaxf(mx.x, v.x); mx.y = fmaxf(mx.y, v.y);
        mx.z = fmaxf(mx.z, v.z); mx.w = fmaxf(mx.w, v.w);
    }
    ssum[t] = sum; smax[t] = mx;
    __syncthreads();
    if (t < 64) {
        float4 s0 = ssum[t], s1 = ssum[t + 64], s2 = ssum[t + 128], s3 = ssum[t + 192];
        float4 m0 = smax[t], m1 = smax[t + 64], m2 = smax[t + 128], m3 = smax[t + 192];
        float4 S, M;
        S.x = (s0.x + s1.x) + (s2.x + s3.x);
        S.y = (s0.y + s1.y) + (s2.y + s3.y);
        S.z = (s0.z + s1.z) + (s2.z + s3.z);
        S.w = (s0.w + s1.w) + (s2.w + s3.w);
        M.x = fmaxf(fmaxf(m0.x, m1.x), fmaxf(m2.x, m3.x));
        M.y = fmaxf(fmaxf(m0.y, m1.y), fmaxf(m2.y, m3.y));
        M.z = fmaxf(fmaxf(m0.z, m1.z), fmaxf(m2.z, m3.z));
        M.w = fmaxf(fmaxf(m0.w, m1.w), fmaxf(m2.w, m3.w));
        *(float4*)&psum_p[(size_t)b * H4 + 4 * q] = S;
        *(float4*)&pmax_p[(size_t)b * H4 + 4 * q] = M;
    }
}

__global__ void __launch_bounds__(256)
k_readout(const float* __restrict__ psum_p, const float* __restrict__ pmax_p,
          const int* __restrict__ gstart,
          const float* __restrict__ W1, const float* __restrict__ b1,
          const float* __restrict__ W2, const float* __restrict__ b2,
          const float* __restrict__ Wo, const float* __restrict__ bo,
          float* __restrict__ out) {
    __shared__ float p0_l[H8];
    __shared__ float p1part[2][H2];
    __shared__ float p1_l[H2];
    __shared__ float p2part[4][H];
    __shared__ float p2_l[H];
    int g = blockIdx.x;
    int t = threadIdx.x;

    {
        float s = 0.f, m = -INFINITY;
#pragma unroll
        for (int k = 0; k < PC; k++) {
            s += psum_p[(size_t)(g * PC + k) * H4 + t];
            m = fmaxf(m, pmax_p[(size_t)(g * PC + k) * H4 + t]);
        }
        int cnt = gstart[g + 1] - gstart[g];
        p0_l[t] = s / fmaxf((float)cnt, 1.f);
        p0_l[H4 + t] = (cnt > 0) ? m : 0.f;
    }
    __syncthreads();

    {
        int j = t & 127, h = t >> 7;
        float acc = 0.f;
        int k0 = h * 256;
        for (int k = 0; k < 256; k++) acc += p0_l[k0 + k] * W1[(k0 + k) * H2 + j];
        p1part[h][j] = acc;
    }
    __syncthreads();
    if (t < H2) p1_l[t] = fmaxf(p1part[0][t] + p1part[1][t] + b1[t], 0.f);
    __syncthreads();

    {
        int c = t & 63, h = t >> 6;
        float acc = 0.f;
        int k0 = h * 32;
        for (int k = 0; k < 32; k++) acc += p1_l[k0 + k] * W2[(k0 + k) * H + c];
        p2part[h][c] = acc;
    }
    __syncthreads();
    if (t < H) p2_l[t] = fmaxf(((p2part[0][t] + p2part[1][t]) + (p2part[2][t] + p2part[3][t])) + b2[t], 0.f);
    __syncthreads();

    if (t < 64) {
        float v = p2_l[t] * Wo[t];
#pragma unroll
        for (int off = 32; off >= 1; off >>= 1) v += __shfl_xor(v, off, 64);
        if (t == 0) out[g] = v + bo[0];
    }
}

extern "C" void kernel_launch(void* const* d_in, const int* in_sizes, int n_in,
                              void* d_out, int out_size, void* d_ws, size_t ws_size,
                              hipStream_t stream) {
    const float* x       = (const float*)d_in[0];
    const int*   ei      = (const int*)d_in[1];
    const int*   batch   = (const int*)d_in[2];
    const float* conv1_W = (const float*)d_in[3];
    const float* conv1_b = (const float*)d_in[4];
    const float* bn1_g   = (const float*)d_in[5];
    const float* bn1_b   = (const float*)d_in[6];
    const float* ln_g    = (const float*)d_in[7];
    const float* ln_b    = (const float*)d_in[8];
    const float* prelu_a = (const float*)d_in[9];
    const float* gen_t   = (const float*)d_in[10];
    const float* mlp_W1  = (const float*)d_in[11];
    const float* mlp_b1  = (const float*)d_in[12];
    const float* mlp_bng = (const float*)d_in[13];
    const float* mlp_bnb = (const float*)d_in[14];
    const float* mlp_W2  = (const float*)d_in[15];
    const float* mlp_b2  = (const float*)d_in[16];
    const float* lin1_W  = (const float*)d_in[17];
    const float* lin1_b  = (const float*)d_in[18];
    const float* lin2_W  = (const float*)d_in[19];
    const float* lin2_b  = (const float*)d_in[20];
    const float* out_W   = (const float*)d_in[21];
    const float* out_b   = (const float*)d_in[22];
    float* out = (float*)d_out;

    float* ws   = (float*)d_ws;
    float* xc   = ws;                          // NND*H4
    float* u    = xc + (size_t)NND * H4;       // NND*H
    float* ua   = u + (size_t)NND * H;         // NND*H (t0 aliases)
    float* t0   = ua;
    float* dinv = ua + (size_t)NND * H;        // NND
    int* rowptr = (int*)(dinv + NND);          // NND+1
    int* next   = rowptr + (NND + 1);          // NND
    int* counts = next + NND;                  // NND
    int* bsum   = counts + NND;                // NB
    int* boff   = bsum + NB;                   // NB
    int* bcur   = boff + NB;                   // NXP
    int* gstart = bcur + NXP;                  // NG+1
    int* csr    = gstart + NG + 1;             // NE
    uintptr_t wb = (uintptr_t)(csr + NE);
    wb = (wb + 15) & ~(uintptr_t)15;
    _Float16* w1f = (_Float16*)wb;             // 3*8192 halves
    _Float16* w2f = w1f + 3 * 8192;            // 3*8192 halves
    uintptr_t eb = (uintptr_t)(w2f + 3 * 8192);
    eb = (eb + 15) & ~(uintptr_t)15;
    uint2* ebuf = (uint2*)eb;                  // NXP*BCAP uint2 (10.24 MB)
    // psum/pmax alias ebuf (dead after scatter; pooling runs last)
    float* psum_p = (float*)ebuf;              // NG*PC*H4
    float* pmax_p = psum_p + (size_t)NG * PC * H4;

    const int B = 256;
    const int gNH  = (NND * H) / B;         // 12500
    const int gMLP = (NND + MT - 1) / MT;   // 782
    const int gE   = (NE + B - 1) / B;      // 4688
    const int gBK  = NXP * NBK;             // 5000

    // ---- setup + bucketized CSR build ----
    k_setup<<<NB + 2 + 12, B, 0, stream>>>(batch, counts, bcur, gstart,
                                           mlp_W1, mlp_W2, w1f, w2f);
    k_bucket<<<gE, B, 0, stream>>>(ei, bcur, ebuf);
    k_count_b<<<gBK, B, 0, stream>>>(bcur, ebuf, counts);
    k_scan1<<<NB, B, 0, stream>>>(counts, rowptr, bsum);
    k_scan2<<<1, B, 0, stream>>>(bsum, boff, rowptr);
    k_scan3<<<NB, B, 0, stream>>>(boff, counts, rowptr, next, dinv);
    k_scatter_b<<<gBK, B, 0, stream>>>(bcur, ebuf, next, csr);

    // ---- GCNConv + LN0/PReLU0 ----
    k_conv1<<<gNH, B, 0, stream>>>(x, conv1_W, t0);
    k_gcn<<<gNH, B, 0, stream>>>(rowptr, csr, t0, dinv, conv1_b, bn1_g, bn1_b,
                                 ln_g, ln_b, prelu_a, xc, u);

    // ---- DeepGCN layers ----
    for (int i = 0; i < 3; i++) {
        k_gen<<<gNH, B, 0, stream>>>(rowptr, csr, u, gen_t, i, ua);
        int do_ln = (i < 2) ? 1 : 0;
        k_mlp<<<gMLP, B, 0, stream>>>(ua,
                                      w1f + (size_t)i * 8192, w2f + (size_t)i * 8192,
                                      mlp_b1 + i * H2,
                                      mlp_bng + i * H2, mlp_bnb + i * H2,
                                      mlp_b2 + i * H,
                                      xc, i,
                                      ln_g + (i + 1) * H, ln_b + (i + 1) * H,
                                      prelu_a + (i + 1) * H, u, do_ln);
    }

    // ---- pooling + readout ----
    k_pool1<<<NG * PC, B, 0, stream>>>(xc, gstart, psum_p, pmax_p);
    k_readout<<<NG, B, 0, stream>>>(psum_p, pmax_p, gstart,
                                    lin1_W, lin1_b, lin2_W, lin2_b, out_W, out_b, out);
}

// Round 11
// 475.701 us; speedup vs baseline: 1.1605x; 1.1059x over previous
//
#include <hip/hip_runtime.h>
#include <math.h>

#define NND 50000
#define NE  1200000
#define NG  256
#define H   64
#define H2  128
#define H4  256
#define H8  512
#define FIN 5
#define EPS_BN 1e-5f
#define EPS_MSG 1e-7f
#define NB 196          // ceil(NND/256)
#define NXP 8           // XCD partitions
#define DPART 6250      // NND / NXP
#define ECH 4688        // ceil(NE/256)
#define PC 8            // pool chunks per graph
#define MT 64           // nodes per mlp block

typedef _Float16 half8 __attribute__((ext_vector_type(8)));
typedef float floatx4 __attribute__((ext_vector_type(4)));

// ---------------- setup: zero counts + gbounds + weight swizzle ----------------

__global__ void k_setup(const int* __restrict__ batch, int* counts, int* __restrict__ gstart,
                        const float* __restrict__ W1, const float* __restrict__ W2,
                        _Float16* __restrict__ w1f, _Float16* __restrict__ w2f) {
    int b = blockIdx.x, t = threadIdx.x;
    if (b < NB) {
        int n = b * 256 + t;
        if (n < NND) counts[n] = 0;
        return;
    }
    if (b == NB || b == NB + 1) {
        int g = (b - NB) * 256 + t;
        if (g > NG) return;
        int lo = 0, hi = NND;
        while (lo < hi) { int mid = (lo + hi) >> 1; if (batch[mid] < g) lo = mid + 1; else hi = mid; }
        gstart[g] = lo;
        return;
    }
    int tt = (b - NB - 2) * 256 + t;
    if (tt >= 3 * 16 * 64) return;
    int lane = tt & 63, fr = (tt >> 6) & 15, l = tt >> 10;
    {
        int jt = fr >> 1, kf = fr & 1;
        int j = jt * 16 + (lane & 15);
        int k0 = kf * 32 + (lane >> 4) * 8;
#pragma unroll
        for (int i = 0; i < 8; i++)
            w1f[(((size_t)l * 16 + jt * 2 + kf) * 64 + lane) * 8 + i] =
                (_Float16)W1[(size_t)l * H * H2 + (k0 + i) * H2 + j];
    }
    {
        int ct = fr >> 2, k2f = fr & 3;
        int c = ct * 16 + (lane & 15);
        int k0 = k2f * 32 + (lane >> 4) * 8;
#pragma unroll
        for (int i = 0; i < 8; i++)
            w2f[(((size_t)l * 16 + ct * 4 + k2f) * 64 + lane) * 8 + i] =
                (_Float16)W2[(size_t)l * H2 * H + (k0 + i) * H + c];
    }
}

// ---------------- CSR build (round-7 proven: 8-pass partitioned) ----------------

__global__ void k_count_p(const int* __restrict__ ei, int* counts) {
    int b = blockIdx.x;
    int g = b & (NXP - 1);
    int e = (b >> 3) * 256 + threadIdx.x;
    if (e >= NE) return;
    int d = ei[NE + e];
    if ((unsigned)(d - g * DPART) < (unsigned)DPART) atomicAdd(&counts[d], 1);
}

__global__ void k_scan1(const int* __restrict__ counts, int* __restrict__ rowptr,
                        int* __restrict__ bsum) {
    __shared__ int wsum[4];
    int b = blockIdx.x, t = threadIdx.x;
    int i = b * 256 + t;
    int v = (i < NND) ? counts[i] : 0;
    int lane = t & 63, wid = t >> 6;
    int sv = v;
#pragma unroll
    for (int off = 1; off < 64; off <<= 1) {
        int x = __shfl_up(sv, off, 64);
        if (lane >= off) sv += x;
    }
    if (lane == 63) wsum[wid] = sv;
    __syncthreads();
    int woff = 0;
    for (int w = 0; w < wid; w++) woff += wsum[w];
    int inc = woff + sv;
    if (i < NND) rowptr[i + 1] = inc;
    if (t == 255) bsum[b] = inc;
}

__global__ void k_scan2(const int* __restrict__ bsum, int* __restrict__ boff,
                        int* __restrict__ rowptr) {
    __shared__ int wsum[4];
    int t = threadIdx.x;
    int v = (t < NB) ? bsum[t] : 0;
    int lane = t & 63, wid = t >> 6;
    int sv = v;
#pragma unroll
    for (int off = 1; off < 64; off <<= 1) {
        int x = __shfl_up(sv, off, 64);
        if (lane >= off) sv += x;
    }
    if (lane == 63) wsum[wid] = sv;
    __syncthreads();
    int woff = 0;
    for (int w = 0; w < wid; w++) woff += wsum[w];
    if (t < NB) boff[t] = woff + sv - v;
    if (t == 0) rowptr[0] = 0;
}

__global__ void k_scan3(const int* __restrict__ boff, const int* __restrict__ counts,
                        int* __restrict__ rowptr, int* __restrict__ next,
                        float* __restrict__ dinv) {
    int i = blockIdx.x * 256 + threadIdx.x;
    if (i >= NND) return;
    int r = rowptr[i + 1] + boff[i >> 8];
    rowptr[i + 1] = r;
    next[i] = r - counts[i];
    dinv[i] = rsqrtf((float)counts[i] + 1.0f);
}

__global__ void k_scatter_p(const int* __restrict__ ei, int* next, int* csr) {
    int b = blockIdx.x;
    int g = b & (NXP - 1);
    int e = (b >> 3) * 256 + threadIdx.x;
    if (e >= NE) return;
    int d = ei[NE + e];
    if ((unsigned)(d - g * DPART) < (unsigned)DPART) {
        int pos = atomicAdd(&next[d], 1);
        csr[pos] = ei[e];
    }
}

// ---------------- GCNConv (4-batched gather: 4 loads in flight) ----------------

__global__ void k_conv1(const float* __restrict__ x, const float* __restrict__ W,
                        float* __restrict__ t0) {
    int tid = blockIdx.x * blockDim.x + threadIdx.x;
    if (tid >= NND * H) return;
    int n = tid >> 6, c = tid & 63;
    float acc = 0.f;
#pragma unroll
    for (int k = 0; k < FIN; k++) acc += x[n * FIN + k] * W[k * H + c];
    t0[n * H + c] = acc;
}

__global__ void k_gcn(const int* __restrict__ rowptr, const int* __restrict__ csr,
                      const float* __restrict__ t0, const float* __restrict__ dinv,
                      const float* __restrict__ cb, const float* __restrict__ bg,
                      const float* __restrict__ bb,
                      const float* __restrict__ lg, const float* __restrict__ lb,
                      const float* __restrict__ pa,
                      float* __restrict__ xc, float* __restrict__ u) {
    int d = (blockIdx.x * blockDim.x + threadIdx.x) >> 6;
    int lane = threadIdx.x & 63;
    if (d >= NND) return;
    int q = lane & 15, eg = lane >> 4;
    int beg = rowptr[d], end = rowptr[d + 1];
    float4 acc = {0.f, 0.f, 0.f, 0.f};
    for (int i0 = beg; i0 < end; i0 += 64) {
        int idx = i0 + lane;
        int csrv = 0; float dvv = 0.f;
        if (idx < end) { csrv = csr[idx]; dvv = dinv[csrv]; }
        int chunk = min(64, end - i0);
        for (int j = 0; j < chunk; j += 16) {
            // batch 4 edges per subgroup: independent loads issued together
            float4 tv[4]; float dv[4]; bool ok[4];
#pragma unroll
            for (int bb2 = 0; bb2 < 4; bb2++) {
                int e_rel = j + 4 * bb2 + eg;
                int s = __shfl(csrv, e_rel, 64);
                dv[bb2] = __shfl(dvv, e_rel, 64);
                ok[bb2] = (e_rel < chunk);
                tv[bb2] = {0.f, 0.f, 0.f, 0.f};
                if (ok[bb2]) tv[bb2] = *(const float4*)&t0[s * H + 4 * q];
            }
#pragma unroll
            for (int bb2 = 0; bb2 < 4; bb2++) {
                if (ok[bb2]) {
                    acc.x += tv[bb2].x * dv[bb2]; acc.y += tv[bb2].y * dv[bb2];
                    acc.z += tv[bb2].z * dv[bb2]; acc.w += tv[bb2].w * dv[bb2];
                }
            }
        }
    }
#pragma unroll
    for (int off = 16; off <= 32; off <<= 1) {
        acc.x += __shfl_xor(acc.x, off, 64);
        acc.y += __shfl_xor(acc.y, off, 64);
        acc.z += __shfl_xor(acc.z, off, 64);
        acc.w += __shfl_xor(acc.w, off, 64);
    }
    if (eg == 0) {
        float dd = dinv[d];
        float4 ts = *(const float4*)&t0[d * H + 4 * q];
        float4 cbv = *(const float4*)&cb[4 * q];
        float4 bgv = *(const float4*)&bg[4 * q];
        float4 bbv = *(const float4*)&bb[4 * q];
        float bns = rsqrtf(1.f + EPS_BN);
        float4 x0;
        x0.x = fmaxf((acc.x * dd + ts.x * dd * dd + cbv.x) * (bgv.x * bns) + bbv.x, 0.f);
        x0.y = fmaxf((acc.y * dd + ts.y * dd * dd + cbv.y) * (bgv.y * bns) + bbv.y, 0.f);
        x0.z = fmaxf((acc.z * dd + ts.z * dd * dd + cbv.z) * (bgv.z * bns) + bbv.z, 0.f);
        x0.w = fmaxf((acc.w * dd + ts.w * dd * dd + cbv.w) * (bgv.w * bns) + bbv.w, 0.f);
        *(float4*)&xc[(size_t)d * H4 + 4 * q] = x0;
        float sum = (x0.x + x0.y) + (x0.z + x0.w);
        float sq  = (x0.x * x0.x + x0.y * x0.y) + (x0.z * x0.z + x0.w * x0.w);
#pragma unroll
        for (int off = 1; off <= 8; off <<= 1) {
            sum += __shfl_xor(sum, off, 64);
            sq  += __shfl_xor(sq,  off, 64);
        }
        float mu  = sum * (1.f / H);
        float var = sq * (1.f / H) - mu * mu;
        float rs = rsqrtf(var + EPS_BN);
        float4 lgv = *(const float4*)&lg[4 * q];
        float4 lbv = *(const float4*)&lb[4 * q];
        float4 pav = *(const float4*)&pa[4 * q];
        float4 y;
        y.x = (x0.x - mu) * rs * lgv.x + lbv.x;
        y.y = (x0.y - mu) * rs * lgv.y + lbv.y;
        y.z = (x0.z - mu) * rs * lgv.z + lbv.z;
        y.w = (x0.w - mu) * rs * lgv.w + lbv.w;
        y.x = (y.x >= 0.f) ? y.x : pav.x * y.x;
        y.y = (y.y >= 0.f) ? y.y : pav.y * y.y;
        y.z = (y.z >= 0.f) ? y.z : pav.z * y.z;
        y.w = (y.w >= 0.f) ? y.w : pav.w * y.w;
        *(float4*)&u[d * H + 4 * q] = y;
    }
}

// ---------------- GENConv softmax aggregation (4-batched gather) ----------------

__global__ void k_gen(const int* __restrict__ rowptr, const int* __restrict__ csr,
                      const float* __restrict__ u, const float* __restrict__ tptr,
                      int li, float* __restrict__ ua) {
    int d = (blockIdx.x * blockDim.x + threadIdx.x) >> 6;
    int lane = threadIdx.x & 63;
    if (d >= NND) return;
    int q = lane & 15, eg = lane >> 4;
    float t = tptr[li];
    int beg = rowptr[d], end = rowptr[d + 1];
    float4 s4 = {0.f, 0.f, 0.f, 0.f}, n4 = {0.f, 0.f, 0.f, 0.f};
    for (int i0 = beg; i0 < end; i0 += 64) {
        int idx = i0 + lane;
        int csrv = (idx < end) ? csr[idx] : 0;
        int chunk = min(64, end - i0);
        for (int j = 0; j < chunk; j += 16) {
            float4 uv[4]; bool ok[4];
#pragma unroll
            for (int bb2 = 0; bb2 < 4; bb2++) {
                int e_rel = j + 4 * bb2 + eg;
                int s = __shfl(csrv, e_rel, 64);
                ok[bb2] = (e_rel < chunk);
                uv[bb2] = {0.f, 0.f, 0.f, 0.f};
                if (ok[bb2]) uv[bb2] = *(const float4*)&u[s * H + 4 * q];
            }
#pragma unroll
            for (int bb2 = 0; bb2 < 4; bb2++) {
                if (ok[bb2]) {
                    float m0 = fmaxf(uv[bb2].x, 0.f) + EPS_MSG;
                    float m1 = fmaxf(uv[bb2].y, 0.f) + EPS_MSG;
                    float m2 = fmaxf(uv[bb2].z, 0.f) + EPS_MSG;
                    float m3 = fmaxf(uv[bb2].w, 0.f) + EPS_MSG;
                    float e0 = __expf(m0 * t - 8.f);
                    float e1 = __expf(m1 * t - 8.f);
                    float e2 = __expf(m2 * t - 8.f);
                    float e3 = __expf(m3 * t - 8.f);
                    s4.x += e0; s4.y += e1; s4.z += e2; s4.w += e3;
                    n4.x += m0 * e0; n4.y += m1 * e1; n4.z += m2 * e2; n4.w += m3 * e3;
                }
            }
        }
    }
#pragma unroll
    for (int off = 16; off <= 32; off <<= 1) {
        s4.x += __shfl_xor(s4.x, off, 64); s4.y += __shfl_xor(s4.y, off, 64);
        s4.z += __shfl_xor(s4.z, off, 64); s4.w += __shfl_xor(s4.w, off, 64);
        n4.x += __shfl_xor(n4.x, off, 64); n4.y += __shfl_xor(n4.y, off, 64);
        n4.z += __shfl_xor(n4.z, off, 64); n4.w += __shfl_xor(n4.w, off, 64);
    }
    if (eg == 0) {
        float4 us = *(const float4*)&u[d * H + 4 * q];
        float4 o;
        o.x = us.x + ((s4.x > 0.f) ? n4.x / s4.x : 0.f);
        o.y = us.y + ((s4.y > 0.f) ? n4.y / s4.y : 0.f);
        o.z = us.z + ((s4.z > 0.f) ? n4.z / s4.z : 0.f);
        o.w = us.w + ((s4.w > 0.f) ? n4.w / s4.w : 0.f);
        *(float4*)&ua[d * H + 4 * q] = o;
    }
}

// ---------------- fused MLP via MFMA (round-7 proven) ----------------

__global__ void __launch_bounds__(256)
k_mlp(const float* __restrict__ ua,
      const _Float16* __restrict__ w1f, const _Float16* __restrict__ w2f,
      const float* __restrict__ b1,
      const float* __restrict__ bng, const float* __restrict__ bnb,
      const float* __restrict__ b2,
      float* __restrict__ xc, int slice,
      const float* __restrict__ lg, const float* __restrict__ lb,
      const float* __restrict__ pa, float* __restrict__ u_next, int do_ln) {
    __shared__ _Float16 a1[4][2][64][8];   // 8 KB
    __shared__ _Float16 a2[4][4][64][8];   // 16 KB
    int t = threadIdx.x;
    int w = t >> 6, l = t & 63;
    int nb = blockIdx.x * MT;
    int c_in = l & 15, quad = l >> 4;
    bool wvalid = (nb + 16 * w) < NND;

    {
        int n = t >> 2;
        int k0 = (t & 3) * 16;
        int gn = nb + n;
        float4 v0 = {0,0,0,0}, v1 = v0, v2 = v0, v3 = v0;
        if (gn < NND) {
            v0 = *(const float4*)&ua[gn * H + k0];
            v1 = *(const float4*)&ua[gn * H + k0 + 4];
            v2 = *(const float4*)&ua[gn * H + k0 + 8];
            v3 = *(const float4*)&ua[gn * H + k0 + 12];
        }
        int mt = n >> 4, kf = k0 >> 5, g0 = (k0 >> 3) & 3;
        half8 h0 = {(_Float16)v0.x, (_Float16)v0.y, (_Float16)v0.z, (_Float16)v0.w,
                    (_Float16)v1.x, (_Float16)v1.y, (_Float16)v1.z, (_Float16)v1.w};
        half8 h1 = {(_Float16)v2.x, (_Float16)v2.y, (_Float16)v2.z, (_Float16)v2.w,
                    (_Float16)v3.x, (_Float16)v3.y, (_Float16)v3.z, (_Float16)v3.w};
        *(half8*)&a1[mt][kf][(n & 15) + 16 * g0][0] = h0;
        *(half8*)&a1[mt][kf][(n & 15) + 16 * (g0 + 1)][0] = h1;
    }

    floatx4 acc[8];
#pragma unroll
    for (int jt = 0; jt < 8; jt++) acc[jt] = (floatx4){0.f, 0.f, 0.f, 0.f};
    half8 af0 = *(half8*)&a1[w][0][l][0];
    half8 af1 = *(half8*)&a1[w][1][l][0];
#pragma unroll
    for (int jt = 0; jt < 8; jt++) {
        half8 bf0 = *(const half8*)&w1f[((size_t)(jt * 2 + 0) * 64 + l) * 8];
        half8 bf1 = *(const half8*)&w1f[((size_t)(jt * 2 + 1) * 64 + l) * 8];
        acc[jt] = __builtin_amdgcn_mfma_f32_16x16x32_f16(af0, bf0, acc[jt], 0, 0, 0);
        acc[jt] = __builtin_amdgcn_mfma_f32_16x16x32_f16(af1, bf1, acc[jt], 0, 0, 0);
    }

    {
        float bns = rsqrtf(1.f + EPS_BN);
#pragma unroll
        for (int jt = 0; jt < 8; jt++) {
            int j = jt * 16 + c_in;
            float b1v = b1[j], bsv = bng[j] * bns, bbv = bnb[j];
            int kf2 = jt >> 1;
            int lp = 16 * ((2 * jt + (c_in >> 3)) & 3);
            int ii = c_in & 7;
#pragma unroll
            for (int reg = 0; reg < 4; reg++) {
                float z = fmaxf((acc[jt][reg] + b1v) * bsv + bbv, 0.f);
                a2[w][kf2][quad * 4 + reg + lp][ii] = (_Float16)z;
            }
        }
    }

    floatx4 acc2[4];
#pragma unroll
    for (int ct = 0; ct < 4; ct++) acc2[ct] = (floatx4){0.f, 0.f, 0.f, 0.f};
    half8 a2f[4];
#pragma unroll
    for (int k2f = 0; k2f < 4; k2f++) a2f[k2f] = *(half8*)&a2[w][k2f][l][0];
#pragma unroll
    for (int ct = 0; ct < 4; ct++) {
#pragma unroll
        for (int k2f = 0; k2f < 4; k2f++) {
            half8 bfr = *(const half8*)&w2f[((size_t)(ct * 4 + k2f) * 64 + l) * 8];
            acc2[ct] = __builtin_amdgcn_mfma_f32_16x16x32_f16(a2f[k2f], bfr, acc2[ct], 0, 0, 0);
        }
    }

    float vv[4][4];
#pragma unroll
    for (int ct = 0; ct < 4; ct++) {
        int c = ct * 16 + c_in;
        float b2v = b2[c];
#pragma unroll
        for (int reg = 0; reg < 4; reg++) {
            int node = nb + 16 * w + quad * 4 + reg;
            float v = 0.f;
            if (wvalid) {
                v = xc[(size_t)node * H4 + slice * H + c] + acc2[ct][reg] + b2v;
                xc[(size_t)node * H4 + (slice + 1) * H + c] = v;
            }
            vv[ct][reg] = v;
        }
    }
    if (do_ln) {
#pragma unroll
        for (int reg = 0; reg < 4; reg++) {
            float s = (vv[0][reg] + vv[1][reg]) + (vv[2][reg] + vv[3][reg]);
            float q = (vv[0][reg] * vv[0][reg] + vv[1][reg] * vv[1][reg]) +
                      (vv[2][reg] * vv[2][reg] + vv[3][reg] * vv[3][reg]);
#pragma unroll
            for (int off = 1; off <= 8; off <<= 1) {
                s += __shfl_xor(s, off, 64);
                q += __shfl_xor(q, off, 64);
            }
            float mu = s * (1.f / H);
            float var = q * (1.f / H) - mu * mu;
            float rs = rsqrtf(var + EPS_BN);
            int node = nb + 16 * w + quad * 4 + reg;
#pragma unroll
            for (int ct = 0; ct < 4; ct++) {
                int c = ct * 16 + c_in;
                float y = (vv[ct][reg] - mu) * rs * lg[c] + lb[c];
                y = (y >= 0.f) ? y : pa[c] * y;
                if (wvalid) u_next[node * H + c] = y;
            }
        }
    }
}

// ---------------- pooling + readout ----------------

__global__ void __launch_bounds__(256)
k_pool1(const float* __restrict__ xc, const int* __restrict__ gstart,
        float* __restrict__ psum_p, float* __restrict__ pmax_p) {
    __shared__ float4 ssum[256];
    __shared__ float4 smax[256];
    int b = blockIdx.x;
    int g = b >> 3, k = b & (PC - 1);
    int t = threadIdx.x;
    int start = gstart[g], end = gstart[g + 1];
    int len = end - start;
    int c0 = start + (len * k) / PC;
    int c1 = start + (len * (k + 1)) / PC;
    int q = t & 63, sub = t >> 6;
    float4 sum = {0.f, 0.f, 0.f, 0.f};
    float4 mx = {-INFINITY, -INFINITY, -INFINITY, -INFINITY};
    for (int n = c0 + sub; n < c1; n += 4) {
        float4 v = *(const float4*)&xc[(size_t)n * H4 + 4 * q];
        sum.x += v.x; sum.y += v.y; sum.z += v.z; sum.w += v.w;
        mx.x = fmaxf(mx.x, v.x); mx.y = fmaxf(mx.y, v.y);
        mx.z = fmaxf(mx.z, v.z); mx.w = fmaxf(mx.w, v.w);
    }
    ssum[t] = sum; smax[t] = mx;
    __syncthreads();
    if (t < 64) {
        float4 s0 = ssum[t], s1 = ssum[t + 64], s2 = ssum[t + 128], s3 = ssum[t + 192];
        float4 m0 = smax[t], m1 = smax[t + 64], m2 = smax[t + 128], m3 = smax[t + 192];
        float4 S, M;
        S.x = (s0.x + s1.x) + (s2.x + s3.x);
        S.y = (s0.y + s1.y) + (s2.y + s3.y);
        S.z = (s0.z + s1.z) + (s2.z + s3.z);
        S.w = (s0.w + s1.w) + (s2.w + s3.w);
        M.x = fmaxf(fmaxf(m0.x, m1.x), fmaxf(m2.x, m3.x));
        M.y = fmaxf(fmaxf(m0.y, m1.y), fmaxf(m2.y, m3.y));
        M.z = fmaxf(fmaxf(m0.z, m1.z), fmaxf(m2.z, m3.z));
        M.w = fmaxf(fmaxf(m0.w, m1.w), fmaxf(m2.w, m3.w));
        *(float4*)&psum_p[(size_t)b * H4 + 4 * q] = S;
        *(float4*)&pmax_p[(size_t)b * H4 + 4 * q] = M;
    }
}

__global__ void __launch_bounds__(256)
k_readout(const float* __restrict__ psum_p, const float* __restrict__ pmax_p,
          const int* __restrict__ gstart,
          const float* __restrict__ W1, const float* __restrict__ b1,
          const float* __restrict__ W2, const float* __restrict__ b2,
          const float* __restrict__ Wo, const float* __restrict__ bo,
          float* __restrict__ out) {
    __shared__ float p0_l[H8];
    __shared__ float p1part[2][H2];
    __shared__ float p1_l[H2];
    __shared__ float p2part[4][H];
    __shared__ float p2_l[H];
    int g = blockIdx.x;
    int t = threadIdx.x;

    {
        float s = 0.f, m = -INFINITY;
#pragma unroll
        for (int k = 0; k < PC; k++) {
            s += psum_p[(size_t)(g * PC + k) * H4 + t];
            m = fmaxf(m, pmax_p[(size_t)(g * PC + k) * H4 + t]);
        }
        int cnt = gstart[g + 1] - gstart[g];
        p0_l[t] = s / fmaxf((float)cnt, 1.f);
        p0_l[H4 + t] = (cnt > 0) ? m : 0.f;
    }
    __syncthreads();

    {
        int j = t & 127, h = t >> 7;
        float acc = 0.f;
        int k0 = h * 256;
        for (int k = 0; k < 256; k++) acc += p0_l[k0 + k] * W1[(k0 + k) * H2 + j];
        p1part[h][j] = acc;
    }
    __syncthreads();
    if (t < H2) p1_l[t] = fmaxf(p1part[0][t] + p1part[1][t] + b1[t], 0.f);
    __syncthreads();

    {
        int c = t & 63, h = t >> 6;
        float acc = 0.f;
        int k0 = h * 32;
        for (int k = 0; k < 32; k++) acc += p1_l[k0 + k] * W2[(k0 + k) * H + c];
        p2part[h][c] = acc;
    }
    __syncthreads();
    if (t < H) p2_l[t] = fmaxf(((p2part[0][t] + p2part[1][t]) + (p2part[2][t] + p2part[3][t])) + b2[t], 0.f);
    __syncthreads();

    if (t < 64) {
        float v = p2_l[t] * Wo[t];
#pragma unroll
        for (int off = 32; off >= 1; off >>= 1) v += __shfl_xor(v, off, 64);
        if (t == 0) out[g] = v + bo[0];
    }
}

extern "C" void kernel_launch(void* const* d_in, const int* in_sizes, int n_in,
                              void* d_out, int out_size, void* d_ws, size_t ws_size,
                              hipStream_t stream) {
    const float* x       = (const float*)d_in[0];
    const int*   ei      = (const int*)d_in[1];
    const int*   batch   = (const int*)d_in[2];
    const float* conv1_W = (const float*)d_in[3];
    const float* conv1_b = (const float*)d_in[4];
    const float* bn1_g   = (const float*)d_in[5];
    const float* bn1_b   = (const float*)d_in[6];
    const float* ln_g    = (const float*)d_in[7];
    const float* ln_b    = (const float*)d_in[8];
    const float* prelu_a = (const float*)d_in[9];
    const float* gen_t   = (const float*)d_in[10];
    const float* mlp_W1  = (const float*)d_in[11];
    const float* mlp_b1  = (const float*)d_in[12];
    const float* mlp_bng = (const float*)d_in[13];
    const float* mlp_bnb = (const float*)d_in[14];
    const float* mlp_W2  = (const float*)d_in[15];
    const float* mlp_b2  = (const float*)d_in[16];
    const float* lin1_W  = (const float*)d_in[17];
    const float* lin1_b  = (const float*)d_in[18];
    const float* lin2_W  = (const float*)d_in[19];
    const float* lin2_b  = (const float*)d_in[20];
    const float* out_W   = (const float*)d_in[21];
    const float* out_b   = (const float*)d_in[22];
    float* out = (float*)d_out;

    float* ws   = (float*)d_ws;
    float* xc   = ws;                          // NND*H4
    float* u    = xc + (size_t)NND * H4;       // NND*H
    float* ua   = u + (size_t)NND * H;         // NND*H (t0 aliases)
    float* t0   = ua;
    float* dinv = ua + (size_t)NND * H;        // NND
    int* rowptr = (int*)(dinv + NND);          // NND+1
    int* next   = rowptr + (NND + 1);          // NND
    int* counts = next + NND;                  // NND
    int* bsum   = counts + NND;                // NB
    int* boff   = bsum + NB;                   // NB
    int* gstart = boff + NB;                   // NG+1
    int* csr    = gstart + NG + 1;             // NE
    uintptr_t wb = (uintptr_t)(csr + NE);
    wb = (wb + 15) & ~(uintptr_t)15;
    _Float16* w1f = (_Float16*)wb;             // 3*8192 halves
    _Float16* w2f = w1f + 3 * 8192;            // 3*8192 halves
    float* psum_p = (float*)(w2f + 3 * 8192);  // NG*PC*H4
    float* pmax_p = psum_p + (size_t)NG * PC * H4;

    const int B = 256;
    const int gNH  = (NND * H) / B;         // 12500
    const int gMLP = (NND + MT - 1) / MT;   // 782
    const int gEP  = NXP * ECH;             // 37504

    // ---- setup + CSR build ----
    k_setup<<<NB + 2 + 12, B, 0, stream>>>(batch, counts, gstart, mlp_W1, mlp_W2, w1f, w2f);
    k_count_p<<<gEP, B, 0, stream>>>(ei, counts);
    k_scan1<<<NB, B, 0, stream>>>(counts, rowptr, bsum);
    k_scan2<<<1, B, 0, stream>>>(bsum, boff, rowptr);
    k_scan3<<<NB, B, 0, stream>>>(boff, counts, rowptr, next, dinv);
    k_scatter_p<<<gEP, B, 0, stream>>>(ei, next, csr);

    // ---- GCNConv + LN0/PReLU0 ----
    k_conv1<<<gNH, B, 0, stream>>>(x, conv1_W, t0);
    k_gcn<<<gNH, B, 0, stream>>>(rowptr, csr, t0, dinv, conv1_b, bn1_g, bn1_b,
                                 ln_g, ln_b, prelu_a, xc, u);

    // ---- DeepGCN layers ----
    for (int i = 0; i < 3; i++) {
        k_gen<<<gNH, B, 0, stream>>>(rowptr, csr, u, gen_t, i, ua);
        int do_ln = (i < 2) ? 1 : 0;
        k_mlp<<<gMLP, B, 0, stream>>>(ua,
                                      w1f + (size_t)i * 8192, w2f + (size_t)i * 8192,
                                      mlp_b1 + i * H2,
                                      mlp_bng + i * H2, mlp_bnb + i * H2,
                                      mlp_b2 + i * H,
                                      xc, i,
                                      ln_g + (i + 1) * H, ln_b + (i + 1) * H,
                                      prelu_a + (i + 1) * H, u, do_ln);
    }

    // ---- pooling + readout ----
    k_pool1<<<NG * PC, B, 0, stream>>>(xc, gstart, psum_p, pmax_p);
    k_readout<<<NG, B, 0, stream>>>(psum_p, pmax_p, gstart,
                                    lin1_W, lin1_b, lin2_W, lin2_b, out_W, out_b, out);
}

// Round 12
// 454.047 us; speedup vs baseline: 1.2159x; 1.0477x over previous
//
#include <hip/hip_runtime.h>
#include <math.h>

#define NND 50000
#define NE  1200000
#define NG  256
#define H   64
#define H2  128
#define H4  256
#define H8  512
#define FIN 5
#define EPS_BN 1e-5f
#define EPS_MSG 1e-7f
#define NB 196          // ceil(NND/256)
#define NXP 8           // XCD partitions
#define DPART 6250      // NND / NXP
#define EC4 1172        // ceil(NE/1024): 4 edges/thread chunks
#define PC 8            // pool chunks per graph
#define MT 64           // nodes per mlp block

typedef _Float16 half8 __attribute__((ext_vector_type(8)));
typedef float floatx4 __attribute__((ext_vector_type(4)));
typedef int intx4 __attribute__((ext_vector_type(4)));

// ---------------- setup: zero counts + gbounds + weight swizzle ----------------

__global__ void k_setup(const int* __restrict__ batch, int* counts, int* __restrict__ gstart,
                        const float* __restrict__ W1, const float* __restrict__ W2,
                        _Float16* __restrict__ w1f, _Float16* __restrict__ w2f) {
    int b = blockIdx.x, t = threadIdx.x;
    if (b < NB) {
        int n = b * 256 + t;
        if (n < NND) counts[n] = 0;
        return;
    }
    if (b == NB || b == NB + 1) {
        int g = (b - NB) * 256 + t;
        if (g > NG) return;
        int lo = 0, hi = NND;
        while (lo < hi) { int mid = (lo + hi) >> 1; if (batch[mid] < g) lo = mid + 1; else hi = mid; }
        gstart[g] = lo;
        return;
    }
    int tt = (b - NB - 2) * 256 + t;
    if (tt >= 3 * 16 * 64) return;
    int lane = tt & 63, fr = (tt >> 6) & 15, l = tt >> 10;
    {
        int jt = fr >> 1, kf = fr & 1;
        int j = jt * 16 + (lane & 15);
        int k0 = kf * 32 + (lane >> 4) * 8;
#pragma unroll
        for (int i = 0; i < 8; i++)
            w1f[(((size_t)l * 16 + jt * 2 + kf) * 64 + lane) * 8 + i] =
                (_Float16)W1[(size_t)l * H * H2 + (k0 + i) * H2 + j];
    }
    {
        int ct = fr >> 2, k2f = fr & 3;
        int c = ct * 16 + (lane & 15);
        int k0 = k2f * 32 + (lane >> 4) * 8;
#pragma unroll
        for (int i = 0; i < 8; i++)
            w2f[(((size_t)l * 16 + ct * 4 + k2f) * 64 + lane) * 8 + i] =
                (_Float16)W2[(size_t)l * H2 * H + (k0 + i) * H + c];
    }
}

// ---------------- CSR build: 4 edges/thread, non-temporal streams ----------------

__global__ void k_count_p(const int* __restrict__ ei, int* counts) {
    int b = blockIdx.x;
    int g = b & (NXP - 1);
    int base = (((b >> 3) * 256) + threadIdx.x) << 2;
    if (base >= NE) return;
    intx4 d4 = __builtin_nontemporal_load((const intx4*)(ei + NE + base));
#pragma unroll
    for (int k = 0; k < 4; k++) {
        int d = d4[k];
        if ((unsigned)(d - g * DPART) < (unsigned)DPART) atomicAdd(&counts[d], 1);
    }
}

__global__ void k_scatter_p(const int* __restrict__ ei, int* next, int* csr) {
    int b = blockIdx.x;
    int g = b & (NXP - 1);
    int base = (((b >> 3) * 256) + threadIdx.x) << 2;
    if (base >= NE) return;
    intx4 d4 = __builtin_nontemporal_load((const intx4*)(ei + NE + base));
    intx4 s4 = __builtin_nontemporal_load((const intx4*)(ei + base));
#pragma unroll
    for (int k = 0; k < 4; k++) {
        int d = d4[k];
        if ((unsigned)(d - g * DPART) < (unsigned)DPART) {
            int pos = atomicAdd(&next[d], 1);
            csr[pos] = s4[k];
        }
    }
}

__global__ void k_scan1(const int* __restrict__ counts, int* __restrict__ rowptr,
                        int* __restrict__ bsum) {
    __shared__ int wsum[4];
    int b = blockIdx.x, t = threadIdx.x;
    int i = b * 256 + t;
    int v = (i < NND) ? counts[i] : 0;
    int lane = t & 63, wid = t >> 6;
    int sv = v;
#pragma unroll
    for (int off = 1; off < 64; off <<= 1) {
        int x = __shfl_up(sv, off, 64);
        if (lane >= off) sv += x;
    }
    if (lane == 63) wsum[wid] = sv;
    __syncthreads();
    int woff = 0;
    for (int w = 0; w < wid; w++) woff += wsum[w];
    int inc = woff + sv;
    if (i < NND) rowptr[i + 1] = inc;
    if (t == 255) bsum[b] = inc;
}

__global__ void k_scan2(const int* __restrict__ bsum, int* __restrict__ boff,
                        int* __restrict__ rowptr) {
    __shared__ int wsum[4];
    int t = threadIdx.x;
    int v = (t < NB) ? bsum[t] : 0;
    int lane = t & 63, wid = t >> 6;
    int sv = v;
#pragma unroll
    for (int off = 1; off < 64; off <<= 1) {
        int x = __shfl_up(sv, off, 64);
        if (lane >= off) sv += x;
    }
    if (lane == 63) wsum[wid] = sv;
    __syncthreads();
    int woff = 0;
    for (int w = 0; w < wid; w++) woff += wsum[w];
    if (t < NB) boff[t] = woff + sv - v;
    if (t == 0) rowptr[0] = 0;
}

__global__ void k_scan3(const int* __restrict__ boff, const int* __restrict__ counts,
                        int* __restrict__ rowptr, int* __restrict__ next,
                        float* __restrict__ dinv) {
    int i = blockIdx.x * 256 + threadIdx.x;
    if (i >= NND) return;
    int r = rowptr[i + 1] + boff[i >> 8];
    rowptr[i + 1] = r;
    next[i] = r - counts[i];
    dinv[i] = rsqrtf((float)counts[i] + 1.0f);
}

// ---------------- GCNConv: factored through K=5 (24 B/edge, L2-resident) ----------------
// Σ_s (x_s W) dinv_s = (Σ_s x_s dinv_s) W ; self term folded with weight dd.

__global__ void k_gcn(const int* __restrict__ rowptr, const int* __restrict__ csr,
                      const float* __restrict__ x, const float* __restrict__ dinv,
                      const float* __restrict__ W,
                      const float* __restrict__ cb, const float* __restrict__ bg,
                      const float* __restrict__ bb,
                      const float* __restrict__ lg, const float* __restrict__ lb,
                      const float* __restrict__ pa,
                      float* __restrict__ xc, float* __restrict__ u) {
    int d = (blockIdx.x * blockDim.x + threadIdx.x) >> 6;
    int lane = threadIdx.x & 63;
    if (d >= NND) return;
    int beg = rowptr[d], end = rowptr[d + 1];
    float xw0 = 0.f, xw1 = 0.f, xw2 = 0.f, xw3 = 0.f, xw4 = 0.f;
    for (int i = beg + lane; i < end; i += 64) {
        int s = csr[i];
        float dv = dinv[s];
        const float* xs = x + s * FIN;
        float a0 = xs[0], a1 = xs[1], a2 = xs[2], a3 = xs[3], a4 = xs[4];
        xw0 += a0 * dv; xw1 += a1 * dv; xw2 += a2 * dv; xw3 += a3 * dv; xw4 += a4 * dv;
    }
#pragma unroll
    for (int off = 1; off <= 32; off <<= 1) {
        xw0 += __shfl_xor(xw0, off, 64);
        xw1 += __shfl_xor(xw1, off, 64);
        xw2 += __shfl_xor(xw2, off, 64);
        xw3 += __shfl_xor(xw3, off, 64);
        xw4 += __shfl_xor(xw4, off, 64);
    }
    float dd = dinv[d];
    const float* xd = x + d * FIN;
    xw0 += dd * xd[0]; xw1 += dd * xd[1]; xw2 += dd * xd[2];
    xw3 += dd * xd[3]; xw4 += dd * xd[4];
    float s_ = xw0 * W[0 * H + lane] + xw1 * W[1 * H + lane] + xw2 * W[2 * H + lane]
             + xw3 * W[3 * H + lane] + xw4 * W[4 * H + lane];
    float v = s_ * dd + cb[lane];
    v = v * (bg[lane] * rsqrtf(1.f + EPS_BN)) + bb[lane];
    float x0 = fmaxf(v, 0.f);
    xc[(size_t)d * H4 + lane] = x0;
    float sum = x0, sq = x0 * x0;
#pragma unroll
    for (int off = 32; off >= 1; off >>= 1) {
        sum += __shfl_xor(sum, off, 64);
        sq  += __shfl_xor(sq,  off, 64);
    }
    float mu  = sum * (1.f / H);
    float var = sq * (1.f / H) - mu * mu;
    float rs = rsqrtf(var + EPS_BN);
    float y = (x0 - mu) * rs * lg[lane] + lb[lane];
    u[d * H + lane] = (y >= 0.f) ? y : pa[lane] * y;
}

// ---------------- GENConv softmax aggregation (4-batched gather) ----------------

__global__ void k_gen(const int* __restrict__ rowptr, const int* __restrict__ csr,
                      const float* __restrict__ u, const float* __restrict__ tptr,
                      int li, float* __restrict__ ua) {
    int d = (blockIdx.x * blockDim.x + threadIdx.x) >> 6;
    int lane = threadIdx.x & 63;
    if (d >= NND) return;
    int q = lane & 15, eg = lane >> 4;
    float t = tptr[li];
    int beg = rowptr[d], end = rowptr[d + 1];
    float4 s4 = {0.f, 0.f, 0.f, 0.f}, n4 = {0.f, 0.f, 0.f, 0.f};
    for (int i0 = beg; i0 < end; i0 += 64) {
        int idx = i0 + lane;
        int csrv = (idx < end) ? csr[idx] : 0;
        int chunk = min(64, end - i0);
        for (int j = 0; j < chunk; j += 16) {
            float4 uv[4]; bool ok[4];
#pragma unroll
            for (int bb2 = 0; bb2 < 4; bb2++) {
                int e_rel = j + 4 * bb2 + eg;
                int s = __shfl(csrv, e_rel, 64);
                ok[bb2] = (e_rel < chunk);
                uv[bb2] = {0.f, 0.f, 0.f, 0.f};
                if (ok[bb2]) uv[bb2] = *(const float4*)&u[s * H + 4 * q];
            }
#pragma unroll
            for (int bb2 = 0; bb2 < 4; bb2++) {
                if (ok[bb2]) {
                    float m0 = fmaxf(uv[bb2].x, 0.f) + EPS_MSG;
                    float m1 = fmaxf(uv[bb2].y, 0.f) + EPS_MSG;
                    float m2 = fmaxf(uv[bb2].z, 0.f) + EPS_MSG;
                    float m3 = fmaxf(uv[bb2].w, 0.f) + EPS_MSG;
                    float e0 = __expf(m0 * t - 8.f);
                    float e1 = __expf(m1 * t - 8.f);
                    float e2 = __expf(m2 * t - 8.f);
                    float e3 = __expf(m3 * t - 8.f);
                    s4.x += e0; s4.y += e1; s4.z += e2; s4.w += e3;
                    n4.x += m0 * e0; n4.y += m1 * e1; n4.z += m2 * e2; n4.w += m3 * e3;
                }
            }
        }
    }
#pragma unroll
    for (int off = 16; off <= 32; off <<= 1) {
        s4.x += __shfl_xor(s4.x, off, 64); s4.y += __shfl_xor(s4.y, off, 64);
        s4.z += __shfl_xor(s4.z, off, 64); s4.w += __shfl_xor(s4.w, off, 64);
        n4.x += __shfl_xor(n4.x, off, 64); n4.y += __shfl_xor(n4.y, off, 64);
        n4.z += __shfl_xor(n4.z, off, 64); n4.w += __shfl_xor(n4.w, off, 64);
    }
    if (eg == 0) {
        float4 us = *(const float4*)&u[d * H + 4 * q];
        float4 o;
        o.x = us.x + ((s4.x > 0.f) ? n4.x / s4.x : 0.f);
        o.y = us.y + ((s4.y > 0.f) ? n4.y / s4.y : 0.f);
        o.z = us.z + ((s4.z > 0.f) ? n4.z / s4.z : 0.f);
        o.w = us.w + ((s4.w > 0.f) ? n4.w / s4.w : 0.f);
        *(float4*)&ua[d * H + 4 * q] = o;
    }
}

// ---------------- fused MLP via MFMA (round-7 proven) ----------------

__global__ void __launch_bounds__(256)
k_mlp(const float* __restrict__ ua,
      const _Float16* __restrict__ w1f, const _Float16* __restrict__ w2f,
      const float* __restrict__ b1,
      const float* __restrict__ bng, const float* __restrict__ bnb,
      const float* __restrict__ b2,
      float* __restrict__ xc, int slice,
      const float* __restrict__ lg, const float* __restrict__ lb,
      const float* __restrict__ pa, float* __restrict__ u_next, int do_ln) {
    __shared__ _Float16 a1[4][2][64][8];   // 8 KB
    __shared__ _Float16 a2[4][4][64][8];   // 16 KB
    int t = threadIdx.x;
    int w = t >> 6, l = t & 63;
    int nb = blockIdx.x * MT;
    int c_in = l & 15, quad = l >> 4;
    bool wvalid = (nb + 16 * w) < NND;

    {
        int n = t >> 2;
        int k0 = (t & 3) * 16;
        int gn = nb + n;
        float4 v0 = {0,0,0,0}, v1 = v0, v2 = v0, v3 = v0;
        if (gn < NND) {
            v0 = *(const float4*)&ua[gn * H + k0];
            v1 = *(const float4*)&ua[gn * H + k0 + 4];
            v2 = *(const float4*)&ua[gn * H + k0 + 8];
            v3 = *(const float4*)&ua[gn * H + k0 + 12];
        }
        int mt = n >> 4, kf = k0 >> 5, g0 = (k0 >> 3) & 3;
        half8 h0 = {(_Float16)v0.x, (_Float16)v0.y, (_Float16)v0.z, (_Float16)v0.w,
                    (_Float16)v1.x, (_Float16)v1.y, (_Float16)v1.z, (_Float16)v1.w};
        half8 h1 = {(_Float16)v2.x, (_Float16)v2.y, (_Float16)v2.z, (_Float16)v2.w,
                    (_Float16)v3.x, (_Float16)v3.y, (_Float16)v3.z, (_Float16)v3.w};
        *(half8*)&a1[mt][kf][(n & 15) + 16 * g0][0] = h0;
        *(half8*)&a1[mt][kf][(n & 15) + 16 * (g0 + 1)][0] = h1;
    }

    floatx4 acc[8];
#pragma unroll
    for (int jt = 0; jt < 8; jt++) acc[jt] = (floatx4){0.f, 0.f, 0.f, 0.f};
    half8 af0 = *(half8*)&a1[w][0][l][0];
    half8 af1 = *(half8*)&a1[w][1][l][0];
#pragma unroll
    for (int jt = 0; jt < 8; jt++) {
        half8 bf0 = *(const half8*)&w1f[((size_t)(jt * 2 + 0) * 64 + l) * 8];
        half8 bf1 = *(const half8*)&w1f[((size_t)(jt * 2 + 1) * 64 + l) * 8];
        acc[jt] = __builtin_amdgcn_mfma_f32_16x16x32_f16(af0, bf0, acc[jt], 0, 0, 0);
        acc[jt] = __builtin_amdgcn_mfma_f32_16x16x32_f16(af1, bf1, acc[jt], 0, 0, 0);
    }

    {
        float bns = rsqrtf(1.f + EPS_BN);
#pragma unroll
        for (int jt = 0; jt < 8; jt++) {
            int j = jt * 16 + c_in;
            float b1v = b1[j], bsv = bng[j] * bns, bbv = bnb[j];
            int kf2 = jt >> 1;
            int lp = 16 * ((2 * jt + (c_in >> 3)) & 3);
            int ii = c_in & 7;
#pragma unroll
            for (int reg = 0; reg < 4; reg++) {
                float z = fmaxf((acc[jt][reg] + b1v) * bsv + bbv, 0.f);
                a2[w][kf2][quad * 4 + reg + lp][ii] = (_Float16)z;
            }
        }
    }

    floatx4 acc2[4];
#pragma unroll
    for (int ct = 0; ct < 4; ct++) acc2[ct] = (floatx4){0.f, 0.f, 0.f, 0.f};
    half8 a2f[4];
#pragma unroll
    for (int k2f = 0; k2f < 4; k2f++) a2f[k2f] = *(half8*)&a2[w][k2f][l][0];
#pragma unroll
    for (int ct = 0; ct < 4; ct++) {
#pragma unroll
        for (int k2f = 0; k2f < 4; k2f++) {
            half8 bfr = *(const half8*)&w2f[((size_t)(ct * 4 + k2f) * 64 + l) * 8];
            acc2[ct] = __builtin_amdgcn_mfma_f32_16x16x32_f16(a2f[k2f], bfr, acc2[ct], 0, 0, 0);
        }
    }

    float vv[4][4];
#pragma unroll
    for (int ct = 0; ct < 4; ct++) {
        int c = ct * 16 + c_in;
        float b2v = b2[c];
#pragma unroll
        for (int reg = 0; reg < 4; reg++) {
            int node = nb + 16 * w + quad * 4 + reg;
            float v = 0.f;
            if (wvalid) {
                v = xc[(size_t)node * H4 + slice * H + c] + acc2[ct][reg] + b2v;
                xc[(size_t)node * H4 + (slice + 1) * H + c] = v;
            }
            vv[ct][reg] = v;
        }
    }
    if (do_ln) {
#pragma unroll
        for (int reg = 0; reg < 4; reg++) {
            float s = (vv[0][reg] + vv[1][reg]) + (vv[2][reg] + vv[3][reg]);
            float q = (vv[0][reg] * vv[0][reg] + vv[1][reg] * vv[1][reg]) +
                      (vv[2][reg] * vv[2][reg] + vv[3][reg] * vv[3][reg]);
#pragma unroll
            for (int off = 1; off <= 8; off <<= 1) {
                s += __shfl_xor(s, off, 64);
                q += __shfl_xor(q, off, 64);
            }
            float mu = s * (1.f / H);
            float var = q * (1.f / H) - mu * mu;
            float rs = rsqrtf(var + EPS_BN);
            int node = nb + 16 * w + quad * 4 + reg;
#pragma unroll
            for (int ct = 0; ct < 4; ct++) {
                int c = ct * 16 + c_in;
                float y = (vv[ct][reg] - mu) * rs * lg[c] + lb[c];
                y = (y >= 0.f) ? y : pa[c] * y;
                if (wvalid) u_next[node * H + c] = y;
            }
        }
    }
}

// ---------------- pooling + readout ----------------

__global__ void __launch_bounds__(256)
k_pool1(const float* __restrict__ xc, const int* __restrict__ gstart,
        float* __restrict__ psum_p, float* __restrict__ pmax_p) {
    __shared__ float4 ssum[256];
    __shared__ float4 smax[256];
    int b = blockIdx.x;
    int g = b >> 3, k = b & (PC - 1);
    int t = threadIdx.x;
    int start = gstart[g], end = gstart[g + 1];
    int len = end - start;
    int c0 = start + (len * k) / PC;
    int c1 = start + (len * (k + 1)) / PC;
    int q = t & 63, sub = t >> 6;
    float4 sum = {0.f, 0.f, 0.f, 0.f};
    float4 mx = {-INFINITY, -INFINITY, -INFINITY, -INFINITY};
    for (int n = c0 + sub; n < c1; n += 4) {
        float4 v = *(const float4*)&xc[(size_t)n * H4 + 4 * q];
        sum.x += v.x; sum.y += v.y; sum.z += v.z; sum.w += v.w;
        mx.x = fmaxf(mx.x, v.x); mx.y = fmaxf(mx.y, v.y);
        mx.z = fmaxf(mx.z, v.z); mx.w = fmaxf(mx.w, v.w);
    }
    ssum[t] = sum; smax[t] = mx;
    __syncthreads();
    if (t < 64) {
        float4 s0 = ssum[t], s1 = ssum[t + 64], s2 = ssum[t + 128], s3 = ssum[t + 192];
        float4 m0 = smax[t], m1 = smax[t + 64], m2 = smax[t + 128], m3 = smax[t + 192];
        float4 S, M;
        S.x = (s0.x + s1.x) + (s2.x + s3.x);
        S.y = (s0.y + s1.y) + (s2.y + s3.y);
        S.z = (s0.z + s1.z) + (s2.z + s3.z);
        S.w = (s0.w + s1.w) + (s2.w + s3.w);
        M.x = fmaxf(fmaxf(m0.x, m1.x), fmaxf(m2.x, m3.x));
        M.y = fmaxf(fmaxf(m0.y, m1.y), fmaxf(m2.y, m3.y));
        M.z = fmaxf(fmaxf(m0.z, m1.z), fmaxf(m2.z, m3.z));
        M.w = fmaxf(fmaxf(m0.w, m1.w), fmaxf(m2.w, m3.w));
        *(float4*)&psum_p[(size_t)b * H4 + 4 * q] = S;
        *(float4*)&pmax_p[(size_t)b * H4 + 4 * q] = M;
    }
}

__global__ void __launch_bounds__(256)
k_readout(const float* __restrict__ psum_p, const float* __restrict__ pmax_p,
          const int* __restrict__ gstart,
          const float* __restrict__ W1, const float* __restrict__ b1,
          const float* __restrict__ W2, const float* __restrict__ b2,
          const float* __restrict__ Wo, const float* __restrict__ bo,
          float* __restrict__ out) {
    __shared__ float p0_l[H8];
    __shared__ float p1part[2][H2];
    __shared__ float p1_l[H2];
    __shared__ float p2part[4][H];
    __shared__ float p2_l[H];
    int g = blockIdx.x;
    int t = threadIdx.x;

    {
        float s = 0.f, m = -INFINITY;
#pragma unroll
        for (int k = 0; k < PC; k++) {
            s += psum_p[(size_t)(g * PC + k) * H4 + t];
            m = fmaxf(m, pmax_p[(size_t)(g * PC + k) * H4 + t]);
        }
        int cnt = gstart[g + 1] - gstart[g];
        p0_l[t] = s / fmaxf((float)cnt, 1.f);
        p0_l[H4 + t] = (cnt > 0) ? m : 0.f;
    }
    __syncthreads();

    {
        int j = t & 127, h = t >> 7;
        float acc = 0.f;
        int k0 = h * 256;
        for (int k = 0; k < 256; k++) acc += p0_l[k0 + k] * W1[(k0 + k) * H2 + j];
        p1part[h][j] = acc;
    }
    __syncthreads();
    if (t < H2) p1_l[t] = fmaxf(p1part[0][t] + p1part[1][t] + b1[t], 0.f);
    __syncthreads();

    {
        int c = t & 63, h = t >> 6;
        float acc = 0.f;
        int k0 = h * 32;
        for (int k = 0; k < 32; k++) acc += p1_l[k0 + k] * W2[(k0 + k) * H + c];
        p2part[h][c] = acc;
    }
    __syncthreads();
    if (t < H) p2_l[t] = fmaxf(((p2part[0][t] + p2part[1][t]) + (p2part[2][t] + p2part[3][t])) + b2[t], 0.f);
    __syncthreads();

    if (t < 64) {
        float v = p2_l[t] * Wo[t];
#pragma unroll
        for (int off = 32; off >= 1; off >>= 1) v += __shfl_xor(v, off, 64);
        if (t == 0) out[g] = v + bo[0];
    }
}

extern "C" void kernel_launch(void* const* d_in, const int* in_sizes, int n_in,
                              void* d_out, int out_size, void* d_ws, size_t ws_size,
                              hipStream_t stream) {
    const float* x       = (const float*)d_in[0];
    const int*   ei      = (const int*)d_in[1];
    const int*   batch   = (const int*)d_in[2];
    const float* conv1_W = (const float*)d_in[3];
    const float* conv1_b = (const float*)d_in[4];
    const float* bn1_g   = (const float*)d_in[5];
    const float* bn1_b   = (const float*)d_in[6];
    const float* ln_g    = (const float*)d_in[7];
    const float* ln_b    = (const float*)d_in[8];
    const float* prelu_a = (const float*)d_in[9];
    const float* gen_t   = (const float*)d_in[10];
    const float* mlp_W1  = (const float*)d_in[11];
    const float* mlp_b1  = (const float*)d_in[12];
    const float* mlp_bng = (const float*)d_in[13];
    const float* mlp_bnb = (const float*)d_in[14];
    const float* mlp_W2  = (const float*)d_in[15];
    const float* mlp_b2  = (const float*)d_in[16];
    const float* lin1_W  = (const float*)d_in[17];
    const float* lin1_b  = (const float*)d_in[18];
    const float* lin2_W  = (const float*)d_in[19];
    const float* lin2_b  = (const float*)d_in[20];
    const float* out_W   = (const float*)d_in[21];
    const float* out_b   = (const float*)d_in[22];
    float* out = (float*)d_out;

    float* ws   = (float*)d_ws;
    float* xc   = ws;                          // NND*H4
    float* u    = xc + (size_t)NND * H4;       // NND*H
    float* ua   = u + (size_t)NND * H;         // NND*H
    float* dinv = ua + (size_t)NND * H;        // NND
    int* rowptr = (int*)(dinv + NND);          // NND+1
    int* next   = rowptr + (NND + 1);          // NND
    int* counts = next + NND;                  // NND
    int* bsum   = counts + NND;                // NB
    int* boff   = bsum + NB;                   // NB
    int* gstart = boff + NB;                   // NG+1
    int* csr    = gstart + NG + 1;             // NE
    uintptr_t wb = (uintptr_t)(csr + NE);
    wb = (wb + 15) & ~(uintptr_t)15;
    _Float16* w1f = (_Float16*)wb;             // 3*8192 halves
    _Float16* w2f = w1f + 3 * 8192;            // 3*8192 halves
    float* psum_p = (float*)(w2f + 3 * 8192);  // NG*PC*H4
    float* pmax_p = psum_p + (size_t)NG * PC * H4;

    const int B = 256;
    const int gNH  = (NND * H) / B;         // 12500
    const int gMLP = (NND + MT - 1) / MT;   // 782
    const int gEP4 = NXP * EC4;             // 9376

    // ---- setup + CSR build ----
    k_setup<<<NB + 2 + 12, B, 0, stream>>>(batch, counts, gstart, mlp_W1, mlp_W2, w1f, w2f);
    k_count_p<<<gEP4, B, 0, stream>>>(ei, counts);
    k_scan1<<<NB, B, 0, stream>>>(counts, rowptr, bsum);
    k_scan2<<<1, B, 0, stream>>>(bsum, boff, rowptr);
    k_scan3<<<NB, B, 0, stream>>>(boff, counts, rowptr, next, dinv);
    k_scatter_p<<<gEP4, B, 0, stream>>>(ei, next, csr);

    // ---- GCNConv (factored) + LN0/PReLU0 ----
    k_gcn<<<gNH, B, 0, stream>>>(rowptr, csr, x, dinv, conv1_W, conv1_b, bn1_g, bn1_b,
                                 ln_g, ln_b, prelu_a, xc, u);

    // ---- DeepGCN layers ----
    for (int i = 0; i < 3; i++) {
        k_gen<<<gNH, B, 0, stream>>>(rowptr, csr, u, gen_t, i, ua);
        int do_ln = (i < 2) ? 1 : 0;
        k_mlp<<<gMLP, B, 0, stream>>>(ua,
                                      w1f + (size_t)i * 8192, w2f + (size_t)i * 8192,
                                      mlp_b1 + i * H2,
                                      mlp_bng + i * H2, mlp_bnb + i * H2,
                                      mlp_b2 + i * H,
                                      xc, i,
                                      ln_g + (i + 1) * H, ln_b + (i + 1) * H,
                                      prelu_a + (i + 1) * H, u, do_ln);
    }

    // ---- pooling + readout ----
    k_pool1<<<NG * PC, B, 0, stream>>>(xc, gstart, psum_p, pmax_p);
    k_readout<<<NG, B, 0, stream>>>(psum_p, pmax_p, gstart,
                                    lin1_W, lin1_b, lin2_W, lin2_b, out_W, out_b, out);
}